// Round 1
// baseline (2277.902 us; speedup 1.0000x reference)
//
#include <hip/hip_runtime.h>
#include <math.h>

#define B_ 8
#define T_ 1024
#define S_ 1024
#define D_ 256
#define H_ 4
#define DH_ 64
#define AUDIO_ 768
#define MOTION_ 33
#define PERIOD_ 30
#define WIN_ 4
#define M_ (B_ * T_)  // 8192 rows for [B*T, D]-shaped activations

// ---------------------------------------------------------------------------
// Generic GEMM: C[m,n] = sum_k A[m,k] * W[n,k] + bias[n]   (optionally ReLU)
// A: [M,K] row-major, W: [N,K] row-major (i.e. the usual x @ W.T layout).
// M % 64 == 0, N % 64 == 0, K % 16 == 0 (true for every call here).
// ---------------------------------------------------------------------------
__global__ __launch_bounds__(256) void gemm_bt(
    const float* __restrict__ A, const float* __restrict__ W,
    const float* __restrict__ bias, float* __restrict__ C,
    int M, int N, int K, int relu) {
  __shared__ float As[16][68];
  __shared__ float Ws[16][68];
  const int bm = blockIdx.x, bn = blockIdx.y;
  const int tid = threadIdx.x;
  const int tx = tid & 15;   // n-dim (4 cols each)
  const int ty = tid >> 4;   // m-dim (4 rows each)
  const float* Ab = A + (size_t)bm * 64 * K;
  const float* Wb = W + (size_t)bn * 64 * K;
  float acc[4][4] = {};
  const int lr = tid >> 2;         // 0..63 row to load
  const int lc = (tid & 3) << 2;   // 0,4,8,12 k-offset

  for (int k0 = 0; k0 < K; k0 += 16) {
    const float4 a = *reinterpret_cast<const float4*>(Ab + (size_t)lr * K + k0 + lc);
    const float4 w = *reinterpret_cast<const float4*>(Wb + (size_t)lr * K + k0 + lc);
    As[lc + 0][lr] = a.x; As[lc + 1][lr] = a.y; As[lc + 2][lr] = a.z; As[lc + 3][lr] = a.w;
    Ws[lc + 0][lr] = w.x; Ws[lc + 1][lr] = w.y; Ws[lc + 2][lr] = w.z; Ws[lc + 3][lr] = w.w;
    __syncthreads();
#pragma unroll
    for (int k = 0; k < 16; ++k) {
      const float4 av = *reinterpret_cast<const float4*>(&As[k][ty << 2]);
      const float4 wv = *reinterpret_cast<const float4*>(&Ws[k][tx << 2]);
      acc[0][0] += av.x * wv.x; acc[0][1] += av.x * wv.y; acc[0][2] += av.x * wv.z; acc[0][3] += av.x * wv.w;
      acc[1][0] += av.y * wv.x; acc[1][1] += av.y * wv.y; acc[1][2] += av.y * wv.z; acc[1][3] += av.y * wv.w;
      acc[2][0] += av.z * wv.x; acc[2][1] += av.z * wv.y; acc[2][2] += av.z * wv.z; acc[2][3] += av.z * wv.w;
      acc[3][0] += av.w * wv.x; acc[3][1] += av.w * wv.y; acc[3][2] += av.w * wv.z; acc[3][3] += av.w * wv.w;
    }
    __syncthreads();
  }

  const int row0 = bm * 64 + (ty << 2);
  const int col0 = bn * 64 + (tx << 2);
  const float4 bv = *reinterpret_cast<const float4*>(bias + col0);
#pragma unroll
  for (int i = 0; i < 4; ++i) {
    float4 r;
    r.x = acc[i][0] + bv.x;
    r.y = acc[i][1] + bv.y;
    r.z = acc[i][2] + bv.z;
    r.w = acc[i][3] + bv.w;
    if (relu) {
      r.x = fmaxf(r.x, 0.f); r.y = fmaxf(r.y, 0.f);
      r.z = fmaxf(r.z, 0.f); r.w = fmaxf(r.w, 0.f);
    }
    *reinterpret_cast<float4*>(C + (size_t)(row0 + i) * N + col0) = r;
  }
}

// ---------------------------------------------------------------------------
// Conv1d k=5 pad=2 over [B,S,D] layout (channels innermost).
// mode 0: Y = gelu_exact(conv(X) + bias)
// mode 1: Y = Y + conv(X) + bias      (residual accumulate, Y pre-filled)
// ---------------------------------------------------------------------------
__global__ __launch_bounds__(256) void conv5k(
    const float* __restrict__ X, const float* __restrict__ W,
    const float* __restrict__ bias, float* Y, int mode) {
  __shared__ float Xs[68][17];        // 68 input positions x 16 channels (+pad)
  __shared__ float Wt[16][5][64];     // [cin][tap][cout]
  const int b = blockIdx.z;
  const int s0 = blockIdx.x * 64;
  const int o0 = blockIdx.y * 64;
  const int tid = threadIdx.x;
  const int tx = tid & 15;  // cout group (4 each)
  const int ty = tid >> 4;  // position group (4 each)
  float acc[4][4] = {};

  for (int c0 = 0; c0 < D_; c0 += 16) {
    for (int i = tid; i < 68 * 16; i += 256) {
      const int p = i >> 4, c = i & 15;
      const int s = s0 + p - 2;
      Xs[p][c] = (s >= 0 && s < S_) ? X[((size_t)b * S_ + s) * D_ + c0 + c] : 0.f;
    }
    for (int i = tid; i < 16 * 5 * 64; i += 256) {
      const int c = i / 320, rem = i % 320, t = rem >> 6, oc = rem & 63;
      Wt[c][t][oc] = W[((size_t)(o0 + oc) * D_ + c0 + c) * 5 + t];
    }
    __syncthreads();
    for (int c = 0; c < 16; ++c) {
#pragma unroll
      for (int t = 0; t < 5; ++t) {
        const float4 wv = *reinterpret_cast<const float4*>(&Wt[c][t][tx << 2]);
        const float x0 = Xs[(ty << 2) + 0 + t][c];
        const float x1 = Xs[(ty << 2) + 1 + t][c];
        const float x2 = Xs[(ty << 2) + 2 + t][c];
        const float x3 = Xs[(ty << 2) + 3 + t][c];
        acc[0][0] += x0 * wv.x; acc[0][1] += x0 * wv.y; acc[0][2] += x0 * wv.z; acc[0][3] += x0 * wv.w;
        acc[1][0] += x1 * wv.x; acc[1][1] += x1 * wv.y; acc[1][2] += x1 * wv.z; acc[1][3] += x1 * wv.w;
        acc[2][0] += x2 * wv.x; acc[2][1] += x2 * wv.y; acc[2][2] += x2 * wv.z; acc[2][3] += x2 * wv.w;
        acc[3][0] += x3 * wv.x; acc[3][1] += x3 * wv.y; acc[3][2] += x3 * wv.z; acc[3][3] += x3 * wv.w;
      }
    }
    __syncthreads();
  }

  const float4 bv = *reinterpret_cast<const float4*>(bias + o0 + (tx << 2));
#pragma unroll
  for (int i = 0; i < 4; ++i) {
    const int s = s0 + (ty << 2) + i;
    float* yp = Y + ((size_t)b * S_ + s) * D_ + o0 + (tx << 2);
    float4 r;
    r.x = acc[i][0] + bv.x;
    r.y = acc[i][1] + bv.y;
    r.z = acc[i][2] + bv.z;
    r.w = acc[i][3] + bv.w;
    if (mode == 0) {  // exact GELU
      r.x = 0.5f * r.x * (1.f + erff(r.x * 0.70710678118654752f));
      r.y = 0.5f * r.y * (1.f + erff(r.y * 0.70710678118654752f));
      r.z = 0.5f * r.z * (1.f + erff(r.z * 0.70710678118654752f));
      r.w = 0.5f * r.w * (1.f + erff(r.w * 0.70710678118654752f));
    } else {
      const float4 old = *reinterpret_cast<const float4*>(yp);
      r.x += old.x; r.y += old.y; r.z += old.z; r.w += old.w;
    }
    *reinterpret_cast<float4*>(yp) = r;
  }
}

// ---------------------------------------------------------------------------
// x = shifted_motion @ W_vm.T + b_vm + PE(t%30)
// one block (256 threads) per (b,t) row; thread = output channel d.
// ---------------------------------------------------------------------------
__global__ __launch_bounds__(256) void motion_pe(
    const float* __restrict__ TM, const float* __restrict__ Wvm,
    const float* __restrict__ bvm, float* __restrict__ Xout) {
  const int d = threadIdx.x;
  const int bt = blockIdx.x;
  const int t = bt & (T_ - 1);
  const int b = bt >> 10;
  float acc = bvm[d];
  if (t > 0) {
    const float* mrow = TM + ((size_t)b * T_ + t - 1) * MOTION_;
    const float* wrow = Wvm + (size_t)d * MOTION_;
#pragma unroll
    for (int m = 0; m < MOTION_; ++m) acc += mrow[m] * wrow[m];
  }
  const int pos = t % PERIOD_;
  const int i2 = d >> 1;
  const float div = expf((float)(2 * i2) * (-9.210340371976184f / 256.f));
  const float ang = (float)pos * div;
  acc += (d & 1) ? cosf(ang) : sinf(ang);
  Xout[(size_t)bt * D_ + d] = acc;
}

// ---------------------------------------------------------------------------
// Self-attention, flash-style. QKV: [B*T, 768] (q|k|v, each col = h*64+dh).
// Grid (T/64, H, B), block = 64 threads (1 wave), thread = 1 query row.
// score = q.k/8 - slope_h * ((t-s)/30)  for s<=t else -inf;  slope_h=0.25^(h+1)
// ---------------------------------------------------------------------------
__global__ __launch_bounds__(64) void self_attn(
    const float* __restrict__ QKV, float* __restrict__ O) {
  __shared__ float Ks[64][68];
  __shared__ float Vs[64][68];
  const int qt = blockIdx.x;
  const int h = blockIdx.y;
  const int b = blockIdx.z;
  const int lane = threadIdx.x;
  const int t = qt * 64 + lane;
  const float slope = exp2f(-2.f * (float)(h + 1));

  // stage Q tile through LDS (coalesced), then to registers
  {
    const size_t rbase = (size_t)b * T_ + (size_t)qt * 64;
    for (int s = lane; s < 64 * 16; s += 64) {
      const int r = s >> 4, c4 = (s & 15) << 2;
      *reinterpret_cast<float4*>(&Ks[r][c4]) =
          *reinterpret_cast<const float4*>(QKV + (rbase + r) * 768 + h * 64 + c4);
    }
  }
  __syncthreads();
  float q[64];
#pragma unroll
  for (int d0 = 0; d0 < 64; d0 += 4) {
    const float4 v = *reinterpret_cast<const float4*>(&Ks[lane][d0]);
    q[d0] = v.x; q[d0 + 1] = v.y; q[d0 + 2] = v.z; q[d0 + 3] = v.w;
  }
  __syncthreads();

  float o[64];
#pragma unroll
  for (int d = 0; d < 64; ++d) o[d] = 0.f;
  float mrun = -1e30f, lrun = 0.f;

  for (int st = 0; st <= qt; ++st) {
    const size_t rbase = (size_t)b * T_ + (size_t)st * 64;
    for (int s = lane; s < 64 * 16; s += 64) {
      const int r = s >> 4, c4 = (s & 15) << 2;
      *reinterpret_cast<float4*>(&Ks[r][c4]) =
          *reinterpret_cast<const float4*>(QKV + (rbase + r) * 768 + 256 + h * 64 + c4);
      *reinterpret_cast<float4*>(&Vs[r][c4]) =
          *reinterpret_cast<const float4*>(QKV + (rbase + r) * 768 + 512 + h * 64 + c4);
    }
    __syncthreads();

    for (int jt = 0; jt < 64; jt += 16) {
      float p[16];
      float tmax = -1e30f;
#pragma unroll
      for (int jj = 0; jj < 16; ++jj) {
        const int j = jt + jj;
        float sc = 0.f;
#pragma unroll
        for (int d0 = 0; d0 < 64; d0 += 4) {
          const float4 kv = *reinterpret_cast<const float4*>(&Ks[j][d0]);
          sc += q[d0] * kv.x + q[d0 + 1] * kv.y + q[d0 + 2] * kv.z + q[d0 + 3] * kv.w;
        }
        const int rel = t - (st * 64 + j);
        sc = (rel >= 0) ? sc * 0.125f - slope * (float)(rel / PERIOD_) : -1e30f;
        p[jj] = sc;
        tmax = fmaxf(tmax, sc);
      }
      const float mnew = fmaxf(mrun, tmax);
      const float scale = __expf(mrun - mnew);
      lrun *= scale;
#pragma unroll
      for (int d = 0; d < 64; ++d) o[d] *= scale;
#pragma unroll
      for (int jj = 0; jj < 16; ++jj) {
        const int j = jt + jj;
        const float pj = __expf(p[jj] - mnew);
        lrun += pj;
#pragma unroll
        for (int d0 = 0; d0 < 64; d0 += 4) {
          const float4 vv = *reinterpret_cast<const float4*>(&Vs[j][d0]);
          o[d0] += pj * vv.x; o[d0 + 1] += pj * vv.y;
          o[d0 + 2] += pj * vv.z; o[d0 + 3] += pj * vv.w;
        }
      }
      mrun = mnew;
    }
    __syncthreads();
  }

  const float inv = 1.f / lrun;
  float* op = O + ((size_t)b * T_ + t) * D_ + h * 64;
#pragma unroll
  for (int d = 0; d < 64; ++d) op[d] = o[d] * inv;
}

// ---------------------------------------------------------------------------
// Cross-attention with band mask |t-j|<=4. Q: [B*T,256], KV: [B*S,512] (k|v).
// One thread per (b,t,h); at most 9 keys, softmax fully in registers.
// ---------------------------------------------------------------------------
__global__ __launch_bounds__(256) void cross_attn(
    const float* __restrict__ Q, const float* __restrict__ KV,
    float* __restrict__ O) {
  const int gid = blockIdx.x * 256 + threadIdx.x;  // 0 .. B*T*H-1
  const int h = gid & 3;
  const int bt = gid >> 2;
  const int t = bt & (T_ - 1);
  const int b = bt >> 10;

  float q[64];
  const float* qp = Q + (size_t)bt * D_ + h * 64;
#pragma unroll
  for (int d0 = 0; d0 < 64; d0 += 4) {
    const float4 v = *reinterpret_cast<const float4*>(qp + d0);
    q[d0] = v.x; q[d0 + 1] = v.y; q[d0 + 2] = v.z; q[d0 + 3] = v.w;
  }

  const int j0 = (t - WIN_ > 0) ? t - WIN_ : 0;
  const int j1 = (t + WIN_ < S_ - 1) ? t + WIN_ : S_ - 1;
  const int nj = j1 - j0 + 1;

  float sc[9];
  float mx = -1e30f;
#pragma unroll
  for (int jj = 0; jj < 9; ++jj) {
    if (jj < nj) {
      const float* kp = KV + ((size_t)b * S_ + j0 + jj) * 512 + h * 64;
      float s = 0.f;
#pragma unroll
      for (int d0 = 0; d0 < 64; d0 += 4) {
        const float4 kv = *reinterpret_cast<const float4*>(kp + d0);
        s += q[d0] * kv.x + q[d0 + 1] * kv.y + q[d0 + 2] * kv.z + q[d0 + 3] * kv.w;
      }
      sc[jj] = s * 0.125f;
      mx = fmaxf(mx, sc[jj]);
    } else {
      sc[jj] = -1e30f;
    }
  }
  float l = 0.f;
  float p[9];
#pragma unroll
  for (int jj = 0; jj < 9; ++jj) { p[jj] = __expf(sc[jj] - mx); l += p[jj]; }
  const float inv = 1.f / l;

  float o[64];
#pragma unroll
  for (int d = 0; d < 64; ++d) o[d] = 0.f;
#pragma unroll
  for (int jj = 0; jj < 9; ++jj) {
    if (jj < nj) {
      const float pj = p[jj] * inv;
      const float* vp = KV + ((size_t)b * S_ + j0 + jj) * 512 + 256 + h * 64;
#pragma unroll
      for (int d0 = 0; d0 < 64; d0 += 4) {
        const float4 vv = *reinterpret_cast<const float4*>(vp + d0);
        o[d0] += pj * vv.x; o[d0 + 1] += pj * vv.y;
        o[d0 + 2] += pj * vv.z; o[d0 + 3] += pj * vv.w;
      }
    }
  }
  float* op = O + (size_t)bt * D_ + h * 64;
#pragma unroll
  for (int d = 0; d < 64; ++d) op[d] = o[d];
}

// ---------------------------------------------------------------------------
// Out = LayerNorm(X + R) * g + b.   One wave per 256-wide row. Out may == X.
// ---------------------------------------------------------------------------
__global__ __launch_bounds__(256) void ln_res(
    const float* X, const float* __restrict__ R,
    const float* __restrict__ g, const float* __restrict__ bta, float* Out) {
  const int wid = threadIdx.x >> 6, lane = threadIdx.x & 63;
  const size_t row = (size_t)blockIdx.x * 4 + wid;
  const float* xp = X + row * D_;
  const float* rp = R + row * D_;
  float v[4];
  float s = 0.f;
#pragma unroll
  for (int k = 0; k < 4; ++k) {
    const int d = lane + k * 64;
    v[k] = xp[d] + rp[d];
    s += v[k];
  }
#pragma unroll
  for (int off = 32; off; off >>= 1) s += __shfl_xor(s, off, 64);
  const float mu = s * (1.f / 256.f);
  float var = 0.f;
#pragma unroll
  for (int k = 0; k < 4; ++k) { const float d = v[k] - mu; var += d * d; }
#pragma unroll
  for (int off = 32; off; off >>= 1) var += __shfl_xor(var, off, 64);
  const float rs = rsqrtf(var * (1.f / 256.f) + 1e-5f);
#pragma unroll
  for (int k = 0; k < 4; ++k) {
    const int d = lane + k * 64;
    Out[row * D_ + d] = (v[k] - mu) * rs * g[d] + bta[d];
  }
}

// ---------------------------------------------------------------------------
// out = clip(x @ W_vr.T + b_vr, 0, 1).  One thread per (row, j<33).
// ---------------------------------------------------------------------------
__global__ __launch_bounds__(256) void head_clip(
    const float* __restrict__ X, const float* __restrict__ Wv,
    const float* __restrict__ bv, float* __restrict__ Out) {
  const int gid = blockIdx.x * 256 + threadIdx.x;
  if (gid >= M_ * MOTION_) return;
  const int j = gid % MOTION_;
  const int row = gid / MOTION_;
  const float4* xr = reinterpret_cast<const float4*>(X + (size_t)row * D_);
  const float4* wr = reinterpret_cast<const float4*>(Wv + (size_t)j * D_);
  float acc = bv[j];
#pragma unroll
  for (int i = 0; i < 64; ++i) {
    const float4 a = xr[i], w = wr[i];
    acc += a.x * w.x + a.y * w.y + a.z * w.z + a.w * w.w;
  }
  Out[gid] = fminf(fmaxf(acc, 0.f), 1.f);
}

// ---------------------------------------------------------------------------
extern "C" void kernel_launch(void* const* d_in, const int* in_sizes, int n_in,
                              void* d_out, int out_size, void* d_ws, size_t ws_size,
                              hipStream_t stream) {
  (void)in_sizes; (void)n_in; (void)out_size; (void)ws_size;
  const float* hidden = (const float*)d_in[0];
  const float* tmot   = (const float*)d_in[1];
  const float* W_af   = (const float*)d_in[2];
  const float* b_af   = (const float*)d_in[3];
  const float* c1w    = (const float*)d_in[4];
  const float* c1b    = (const float*)d_in[5];
  const float* c2w    = (const float*)d_in[6];
  const float* c2b    = (const float*)d_in[7];
  const float* Wvm    = (const float*)d_in[8];
  const float* bvm    = (const float*)d_in[9];
  const float* sa_in_w  = (const float*)d_in[10];
  const float* sa_in_b  = (const float*)d_in[11];
  const float* sa_out_w = (const float*)d_in[12];
  const float* sa_out_b = (const float*)d_in[13];
  const float* ca_in_w  = (const float*)d_in[14];
  const float* ca_in_b  = (const float*)d_in[15];
  const float* ca_out_w = (const float*)d_in[16];
  const float* ca_out_b = (const float*)d_in[17];
  const float* ln1g = (const float*)d_in[18];
  const float* ln1b = (const float*)d_in[19];
  const float* ln2g = (const float*)d_in[20];
  const float* ln2b = (const float*)d_in[21];
  const float* ln3g = (const float*)d_in[22];
  const float* ln3b = (const float*)d_in[23];
  const float* ff1w = (const float*)d_in[24];
  const float* ff1b = (const float*)d_in[25];
  const float* ff2w = (const float*)d_in[26];
  const float* ff2b = (const float*)d_in[27];
  const float* Wvr  = (const float*)d_in[28];
  const float* bvr  = (const float*)d_in[29];
  float* out = (float*)d_out;

  float* ws = (float*)d_ws;
  const size_t BSD = (size_t)B_ * T_ * D_;  // 2,097,152 floats
  float* audio = ws;            // [B*S, 256]
  float* x     = ws + BSD;      // [B*T, 256]
  float* att   = ws + 2 * BSD;  // [B*T, 256]
  float* t1    = ws + 3 * BSD;  // [B*T, 256] scratch (also conv1 output)
  float* qkv   = ws + 4 * BSD;  // [B*T, 768] / reused for q, kv, ffn hidden

  const dim3 blk(256);

  // audio front-end
  gemm_bt<<<dim3(M_ / 64, D_ / 64), blk, 0, stream>>>(hidden, W_af, b_af, audio, M_, D_, AUDIO_, 0);
  conv5k<<<dim3(S_ / 64, D_ / 64, B_), blk, 0, stream>>>(audio, c1w, c1b, t1, 0);
  conv5k<<<dim3(S_ / 64, D_ / 64, B_), blk, 0, stream>>>(t1, c2w, c2b, audio, 1);

  // motion embedding + PE
  motion_pe<<<dim3(M_), blk, 0, stream>>>(tmot, Wvm, bvm, x);

  for (int l = 0; l < 2; ++l) {
    // self-attention
    gemm_bt<<<dim3(M_ / 64, 768 / 64), blk, 0, stream>>>(
        x, sa_in_w + (size_t)l * 768 * 256, sa_in_b + l * 768, qkv, M_, 768, 256, 0);
    self_attn<<<dim3(T_ / 64, H_, B_), dim3(64), 0, stream>>>(qkv, att);
    gemm_bt<<<dim3(M_ / 64, 256 / 64), blk, 0, stream>>>(
        att, sa_out_w + (size_t)l * 256 * 256, sa_out_b + l * 256, t1, M_, 256, 256, 0);
    ln_res<<<dim3(M_ / 4), blk, 0, stream>>>(x, t1, ln1g + l * 256, ln1b + l * 256, x);

    // cross-attention (banded)
    gemm_bt<<<dim3(M_ / 64, 256 / 64), blk, 0, stream>>>(
        x, ca_in_w + (size_t)l * 768 * 256, ca_in_b + l * 768, qkv, M_, 256, 256, 0);
    gemm_bt<<<dim3(M_ / 64, 512 / 64), blk, 0, stream>>>(
        audio, ca_in_w + (size_t)l * 768 * 256 + 256 * 256, ca_in_b + l * 768 + 256,
        qkv + BSD, M_, 512, 256, 0);
    cross_attn<<<dim3(M_ * H_ / 256), blk, 0, stream>>>(qkv, qkv + BSD, att);
    gemm_bt<<<dim3(M_ / 64, 256 / 64), blk, 0, stream>>>(
        att, ca_out_w + (size_t)l * 256 * 256, ca_out_b + l * 256, t1, M_, 256, 256, 0);
    ln_res<<<dim3(M_ / 4), blk, 0, stream>>>(x, t1, ln2g + l * 256, ln2b + l * 256, x);

    // FFN
    gemm_bt<<<dim3(M_ / 64, 512 / 64), blk, 0, stream>>>(
        x, ff1w + (size_t)l * 512 * 256, ff1b + l * 512, qkv, M_, 512, 256, 1);
    gemm_bt<<<dim3(M_ / 64, 256 / 64), blk, 0, stream>>>(
        qkv, ff2w + (size_t)l * 256 * 512, ff2b + l * 256, t1, M_, 256, 512, 0);
    ln_res<<<dim3(M_ / 4), blk, 0, stream>>>(x, t1, ln3g + l * 256, ln3b + l * 256, x);
  }

  head_clip<<<dim3((M_ * MOTION_ + 255) / 256), blk, 0, stream>>>(x, Wvr, bvr, out);
}

// Round 2
// 1374.418 us; speedup vs baseline: 1.6574x; 1.6574x over previous
//
#include <hip/hip_runtime.h>
#include <math.h>

#define B_ 8
#define T_ 1024
#define S_ 1024
#define D_ 256
#define H_ 4
#define DH_ 64
#define AUDIO_ 768
#define MOTION_ 33
#define PERIOD_ 30
#define WIN_ 4
#define M_ (B_ * T_)  // 8192 rows for [B*T, D]-shaped activations

// ---------------------------------------------------------------------------
// Generic GEMM: C[m,n] = sum_k A[m,k] * W[n,k] + bias[n]   (optionally ReLU)
// A: [M,K] row-major, W: [N,K] row-major (i.e. the usual x @ W.T layout).
// M % 64 == 0, N % 64 == 0, K % 16 == 0 (true for every call here).
// ---------------------------------------------------------------------------
__global__ __launch_bounds__(256) void gemm_bt(
    const float* __restrict__ A, const float* __restrict__ W,
    const float* __restrict__ bias, float* __restrict__ C,
    int M, int N, int K, int relu) {
  __shared__ float As[16][68];
  __shared__ float Ws[16][68];
  const int bm = blockIdx.x, bn = blockIdx.y;
  const int tid = threadIdx.x;
  const int tx = tid & 15;   // n-dim (4 cols each)
  const int ty = tid >> 4;   // m-dim (4 rows each)
  const float* Ab = A + (size_t)bm * 64 * K;
  const float* Wb = W + (size_t)bn * 64 * K;
  float acc[4][4] = {};
  const int lr = tid >> 2;         // 0..63 row to load
  const int lc = (tid & 3) << 2;   // 0,4,8,12 k-offset

  for (int k0 = 0; k0 < K; k0 += 16) {
    const float4 a = *reinterpret_cast<const float4*>(Ab + (size_t)lr * K + k0 + lc);
    const float4 w = *reinterpret_cast<const float4*>(Wb + (size_t)lr * K + k0 + lc);
    As[lc + 0][lr] = a.x; As[lc + 1][lr] = a.y; As[lc + 2][lr] = a.z; As[lc + 3][lr] = a.w;
    Ws[lc + 0][lr] = w.x; Ws[lc + 1][lr] = w.y; Ws[lc + 2][lr] = w.z; Ws[lc + 3][lr] = w.w;
    __syncthreads();
#pragma unroll
    for (int k = 0; k < 16; ++k) {
      const float4 av = *reinterpret_cast<const float4*>(&As[k][ty << 2]);
      const float4 wv = *reinterpret_cast<const float4*>(&Ws[k][tx << 2]);
      acc[0][0] += av.x * wv.x; acc[0][1] += av.x * wv.y; acc[0][2] += av.x * wv.z; acc[0][3] += av.x * wv.w;
      acc[1][0] += av.y * wv.x; acc[1][1] += av.y * wv.y; acc[1][2] += av.y * wv.z; acc[1][3] += av.y * wv.w;
      acc[2][0] += av.z * wv.x; acc[2][1] += av.z * wv.y; acc[2][2] += av.z * wv.z; acc[2][3] += av.z * wv.w;
      acc[3][0] += av.w * wv.x; acc[3][1] += av.w * wv.y; acc[3][2] += av.w * wv.z; acc[3][3] += av.w * wv.w;
    }
    __syncthreads();
  }

  const int row0 = bm * 64 + (ty << 2);
  const int col0 = bn * 64 + (tx << 2);
  const float4 bv = *reinterpret_cast<const float4*>(bias + col0);
#pragma unroll
  for (int i = 0; i < 4; ++i) {
    float4 r;
    r.x = acc[i][0] + bv.x;
    r.y = acc[i][1] + bv.y;
    r.z = acc[i][2] + bv.z;
    r.w = acc[i][3] + bv.w;
    if (relu) {
      r.x = fmaxf(r.x, 0.f); r.y = fmaxf(r.y, 0.f);
      r.z = fmaxf(r.z, 0.f); r.w = fmaxf(r.w, 0.f);
    }
    *reinterpret_cast<float4*>(C + (size_t)(row0 + i) * N + col0) = r;
  }
}

// ---------------------------------------------------------------------------
// Conv1d k=5 pad=2 over [B,S,D] layout (channels innermost).
// mode 0: Y = gelu_exact(conv(X) + bias)
// mode 1: Y = Y + conv(X) + bias      (residual accumulate, Y pre-filled)
// ---------------------------------------------------------------------------
__global__ __launch_bounds__(256) void conv5k(
    const float* __restrict__ X, const float* __restrict__ W,
    const float* __restrict__ bias, float* Y, int mode) {
  __shared__ float Xs[68][17];        // 68 input positions x 16 channels (+pad)
  __shared__ float Wt[16][5][64];     // [cin][tap][cout]
  const int b = blockIdx.z;
  const int s0 = blockIdx.x * 64;
  const int o0 = blockIdx.y * 64;
  const int tid = threadIdx.x;
  const int tx = tid & 15;  // cout group (4 each)
  const int ty = tid >> 4;  // position group (4 each)
  float acc[4][4] = {};

  for (int c0 = 0; c0 < D_; c0 += 16) {
    for (int i = tid; i < 68 * 16; i += 256) {
      const int p = i >> 4, c = i & 15;
      const int s = s0 + p - 2;
      Xs[p][c] = (s >= 0 && s < S_) ? X[((size_t)b * S_ + s) * D_ + c0 + c] : 0.f;
    }
    for (int i = tid; i < 16 * 5 * 64; i += 256) {
      const int c = i / 320, rem = i % 320, t = rem >> 6, oc = rem & 63;
      Wt[c][t][oc] = W[((size_t)(o0 + oc) * D_ + c0 + c) * 5 + t];
    }
    __syncthreads();
    for (int c = 0; c < 16; ++c) {
#pragma unroll
      for (int t = 0; t < 5; ++t) {
        const float4 wv = *reinterpret_cast<const float4*>(&Wt[c][t][tx << 2]);
        const float x0 = Xs[(ty << 2) + 0 + t][c];
        const float x1 = Xs[(ty << 2) + 1 + t][c];
        const float x2 = Xs[(ty << 2) + 2 + t][c];
        const float x3 = Xs[(ty << 2) + 3 + t][c];
        acc[0][0] += x0 * wv.x; acc[0][1] += x0 * wv.y; acc[0][2] += x0 * wv.z; acc[0][3] += x0 * wv.w;
        acc[1][0] += x1 * wv.x; acc[1][1] += x1 * wv.y; acc[1][2] += x1 * wv.z; acc[1][3] += x1 * wv.w;
        acc[2][0] += x2 * wv.x; acc[2][1] += x2 * wv.y; acc[2][2] += x2 * wv.z; acc[2][3] += x2 * wv.w;
        acc[3][0] += x3 * wv.x; acc[3][1] += x3 * wv.y; acc[3][2] += x3 * wv.z; acc[3][3] += x3 * wv.w;
      }
    }
    __syncthreads();
  }

  const float4 bv = *reinterpret_cast<const float4*>(bias + o0 + (tx << 2));
#pragma unroll
  for (int i = 0; i < 4; ++i) {
    const int s = s0 + (ty << 2) + i;
    float* yp = Y + ((size_t)b * S_ + s) * D_ + o0 + (tx << 2);
    float4 r;
    r.x = acc[i][0] + bv.x;
    r.y = acc[i][1] + bv.y;
    r.z = acc[i][2] + bv.z;
    r.w = acc[i][3] + bv.w;
    if (mode == 0) {  // exact GELU
      r.x = 0.5f * r.x * (1.f + erff(r.x * 0.70710678118654752f));
      r.y = 0.5f * r.y * (1.f + erff(r.y * 0.70710678118654752f));
      r.z = 0.5f * r.z * (1.f + erff(r.z * 0.70710678118654752f));
      r.w = 0.5f * r.w * (1.f + erff(r.w * 0.70710678118654752f));
    } else {
      const float4 old = *reinterpret_cast<const float4*>(yp);
      r.x += old.x; r.y += old.y; r.z += old.z; r.w += old.w;
    }
    *reinterpret_cast<float4*>(yp) = r;
  }
}

// ---------------------------------------------------------------------------
// x = shifted_motion @ W_vm.T + b_vm + PE(t%30)
// ---------------------------------------------------------------------------
__global__ __launch_bounds__(256) void motion_pe(
    const float* __restrict__ TM, const float* __restrict__ Wvm,
    const float* __restrict__ bvm, float* __restrict__ Xout) {
  const int d = threadIdx.x;
  const int bt = blockIdx.x;
  const int t = bt & (T_ - 1);
  const int b = bt >> 10;
  float acc = bvm[d];
  if (t > 0) {
    const float* mrow = TM + ((size_t)b * T_ + t - 1) * MOTION_;
    const float* wrow = Wvm + (size_t)d * MOTION_;
#pragma unroll
    for (int m = 0; m < MOTION_; ++m) acc += mrow[m] * wrow[m];
  }
  const int pos = t % PERIOD_;
  const int i2 = d >> 1;
  const float div = expf((float)(2 * i2) * (-9.210340371976184f / 256.f));
  const float ang = (float)pos * div;
  acc += (d & 1) ? cosf(ang) : sinf(ang);
  Xout[(size_t)bt * D_ + d] = acc;
}

// ---------------------------------------------------------------------------
// Self-attention, flash-decoding style.
// QKV: [B*T, 768] (q|k|v, each col = h*64+dh). Grid (T/64, H, B), 256 thr.
// 4 waves per block; causal key range split across waves in 32-key slices
// from a cooperatively staged 128-key LDS round. Per-wave online softmax,
// merged through LDS at the end (O-partials reuse the K/V buffer).
// score = q.k/8 - slope_h * ((t-s)/30)  for s<=t else -inf; slope_h=0.25^(h+1)
// ---------------------------------------------------------------------------
__global__ __launch_bounds__(256) void self_attn(
    const float* __restrict__ QKV, float* __restrict__ O) {
  __shared__ float smem[256 * 68];   // K rows 0..127, V rows 128..255 (stride 68)
  __shared__ float Mp[4][64], Lp[4][64];
  const int qt = blockIdx.x;
  const int h = blockIdx.y;
  const int b = blockIdx.z;
  const int tid = threadIdx.x;
  const int wave = tid >> 6, lane = tid & 63;
  const int t = qt * 64 + lane;
  const float slope = exp2f(-2.f * (float)(h + 1));
  const size_t qkbase = ((size_t)b * T_) * 768 + h * 64;

  // stage Q tile (rows 0..63) coalesced, then to registers
  for (int idx = tid; idx < 64 * 16; idx += 256) {
    const int r = idx >> 4, c4 = (idx & 15) << 2;
    *reinterpret_cast<float4*>(&smem[r * 68 + c4]) =
        *reinterpret_cast<const float4*>(QKV + qkbase + (size_t)(qt * 64 + r) * 768 + c4);
  }
  __syncthreads();
  float q[64];
#pragma unroll
  for (int d0 = 0; d0 < 64; d0 += 4) {
    const float4 v = *reinterpret_cast<const float4*>(&smem[lane * 68 + d0]);
    q[d0] = v.x; q[d0 + 1] = v.y; q[d0 + 2] = v.z; q[d0 + 3] = v.w;
  }
  __syncthreads();

  float o[64];
#pragma unroll
  for (int d = 0; d < 64; ++d) o[d] = 0.f;
  float mrun = -1e30f, lrun = 0.f;

  const int nkey = (qt + 1) * 64;  // causal key count for this query tile
  for (int k0 = 0; k0 < nkey; k0 += 128) {
    const int cnt = min(128, nkey - k0);  // 64 or 128, multiple of 32
    for (int idx = tid; idx < cnt * 16; idx += 256) {
      const int r = idx >> 4, c4 = (idx & 15) << 2;
      const size_t rowoff = qkbase + (size_t)(k0 + r) * 768;
      *reinterpret_cast<float4*>(&smem[r * 68 + c4]) =
          *reinterpret_cast<const float4*>(QKV + rowoff + 256 + c4);
      *reinterpret_cast<float4*>(&smem[(128 + r) * 68 + c4]) =
          *reinterpret_cast<const float4*>(QKV + rowoff + 512 + c4);
    }
    __syncthreads();

    const int kw0 = wave * 32;  // this wave's slice within the round
    if (kw0 < cnt) {
      for (int jt = 0; jt < 32; jt += 16) {
        float p[16];
        float tmax = -1e30f;
#pragma unroll
        for (int jj = 0; jj < 16; ++jj) {
          const int r = kw0 + jt + jj;
          float sc = 0.f;
#pragma unroll
          for (int d0 = 0; d0 < 64; d0 += 4) {
            const float4 kv = *reinterpret_cast<const float4*>(&smem[r * 68 + d0]);
            sc += q[d0] * kv.x + q[d0 + 1] * kv.y + q[d0 + 2] * kv.z + q[d0 + 3] * kv.w;
          }
          const int rel = t - (k0 + r);
          sc = (rel >= 0) ? sc * 0.125f - slope * (float)(rel / PERIOD_) : -1e30f;
          p[jj] = sc;
          tmax = fmaxf(tmax, sc);
        }
        const float mnew = fmaxf(mrun, tmax);
        const float scale = __expf(mrun - mnew);
        lrun *= scale;
#pragma unroll
        for (int d = 0; d < 64; ++d) o[d] *= scale;
#pragma unroll
        for (int jj = 0; jj < 16; ++jj) {
          const int r = 128 + kw0 + jt + jj;
          const float pj = __expf(p[jj] - mnew);
          lrun += pj;
#pragma unroll
          for (int d0 = 0; d0 < 64; d0 += 4) {
            const float4 vv = *reinterpret_cast<const float4*>(&smem[r * 68 + d0]);
            o[d0] += pj * vv.x; o[d0 + 1] += pj * vv.y;
            o[d0 + 2] += pj * vv.z; o[d0 + 3] += pj * vv.w;
          }
        }
        mrun = mnew;
      }
    }
    __syncthreads();
  }

  // write per-wave partials (reuse smem rows: row = wave*64 + lane)
  {
    float* orow = &smem[(wave * 64 + lane) * 68];
#pragma unroll
    for (int d0 = 0; d0 < 64; d0 += 4) {
      float4 v; v.x = o[d0]; v.y = o[d0 + 1]; v.z = o[d0 + 2]; v.w = o[d0 + 3];
      *reinterpret_cast<float4*>(&orow[d0]) = v;
    }
    Mp[wave][lane] = mrun;
    Lp[wave][lane] = lrun;
  }
  __syncthreads();

  // combine: thread (part, qq) handles dims [part*16, part*16+16)
  const int qq = tid & 63, part = tid >> 6;
  const float m = fmaxf(fmaxf(Mp[0][qq], Mp[1][qq]), fmaxf(Mp[2][qq], Mp[3][qq]));
  const float s0 = __expf(Mp[0][qq] - m);
  const float s1 = __expf(Mp[1][qq] - m);
  const float s2 = __expf(Mp[2][qq] - m);
  const float s3 = __expf(Mp[3][qq] - m);
  const float l = Lp[0][qq] * s0 + Lp[1][qq] * s1 + Lp[2][qq] * s2 + Lp[3][qq] * s3;
  const float inv = 1.f / l;
  float* op = O + ((size_t)b * T_ + qt * 64 + qq) * D_ + h * 64 + part * 16;
#pragma unroll
  for (int d0 = 0; d0 < 16; d0 += 4) {
    const int c = part * 16 + d0;
    const float4 a0 = *reinterpret_cast<const float4*>(&smem[(0 * 64 + qq) * 68 + c]);
    const float4 a1 = *reinterpret_cast<const float4*>(&smem[(1 * 64 + qq) * 68 + c]);
    const float4 a2 = *reinterpret_cast<const float4*>(&smem[(2 * 64 + qq) * 68 + c]);
    const float4 a3 = *reinterpret_cast<const float4*>(&smem[(3 * 64 + qq) * 68 + c]);
    float4 r;
    r.x = (a0.x * s0 + a1.x * s1 + a2.x * s2 + a3.x * s3) * inv;
    r.y = (a0.y * s0 + a1.y * s1 + a2.y * s2 + a3.y * s3) * inv;
    r.z = (a0.z * s0 + a1.z * s1 + a2.z * s2 + a3.z * s3) * inv;
    r.w = (a0.w * s0 + a1.w * s1 + a2.w * s2 + a3.w * s3) * inv;
    *reinterpret_cast<float4*>(op + d0) = r;
  }
}

// ---------------------------------------------------------------------------
// Cross-attention with band mask |t-j|<=4. Q: [B*T,256], KV: [B*S,512] (k|v).
// One thread per (b,t,h); at most 9 keys, softmax fully in registers.
// ---------------------------------------------------------------------------
__global__ __launch_bounds__(256) void cross_attn(
    const float* __restrict__ Q, const float* __restrict__ KV,
    float* __restrict__ O) {
  const int gid = blockIdx.x * 256 + threadIdx.x;  // 0 .. B*T*H-1
  const int h = gid & 3;
  const int bt = gid >> 2;
  const int t = bt & (T_ - 1);
  const int b = bt >> 10;

  float q[64];
  const float* qp = Q + (size_t)bt * D_ + h * 64;
#pragma unroll
  for (int d0 = 0; d0 < 64; d0 += 4) {
    const float4 v = *reinterpret_cast<const float4*>(qp + d0);
    q[d0] = v.x; q[d0 + 1] = v.y; q[d0 + 2] = v.z; q[d0 + 3] = v.w;
  }

  const int j0 = (t - WIN_ > 0) ? t - WIN_ : 0;
  const int j1 = (t + WIN_ < S_ - 1) ? t + WIN_ : S_ - 1;
  const int nj = j1 - j0 + 1;

  float sc[9];
  float mx = -1e30f;
#pragma unroll
  for (int jj = 0; jj < 9; ++jj) {
    if (jj < nj) {
      const float* kp = KV + ((size_t)b * S_ + j0 + jj) * 512 + h * 64;
      float s = 0.f;
#pragma unroll
      for (int d0 = 0; d0 < 64; d0 += 4) {
        const float4 kv = *reinterpret_cast<const float4*>(kp + d0);
        s += q[d0] * kv.x + q[d0 + 1] * kv.y + q[d0 + 2] * kv.z + q[d0 + 3] * kv.w;
      }
      sc[jj] = s * 0.125f;
      mx = fmaxf(mx, sc[jj]);
    } else {
      sc[jj] = -1e30f;
    }
  }
  float l = 0.f;
  float p[9];
#pragma unroll
  for (int jj = 0; jj < 9; ++jj) { p[jj] = __expf(sc[jj] - mx); l += p[jj]; }
  const float inv = 1.f / l;

  float o[64];
#pragma unroll
  for (int d = 0; d < 64; ++d) o[d] = 0.f;
#pragma unroll
  for (int jj = 0; jj < 9; ++jj) {
    if (jj < nj) {
      const float pj = p[jj] * inv;
      const float* vp = KV + ((size_t)b * S_ + j0 + jj) * 512 + 256 + h * 64;
#pragma unroll
      for (int d0 = 0; d0 < 64; d0 += 4) {
        const float4 vv = *reinterpret_cast<const float4*>(vp + d0);
        o[d0] += pj * vv.x; o[d0 + 1] += pj * vv.y;
        o[d0 + 2] += pj * vv.z; o[d0 + 3] += pj * vv.w;
      }
    }
  }
  float* op = O + (size_t)bt * D_ + h * 64;
#pragma unroll
  for (int d = 0; d < 64; ++d) op[d] = o[d];
}

// ---------------------------------------------------------------------------
// Out = LayerNorm(X + R) * g + b.   One wave per 256-wide row. Out may == X.
// ---------------------------------------------------------------------------
__global__ __launch_bounds__(256) void ln_res(
    const float* X, const float* __restrict__ R,
    const float* __restrict__ g, const float* __restrict__ bta, float* Out) {
  const int wid = threadIdx.x >> 6, lane = threadIdx.x & 63;
  const size_t row = (size_t)blockIdx.x * 4 + wid;
  const float* xp = X + row * D_;
  const float* rp = R + row * D_;
  float v[4];
  float s = 0.f;
#pragma unroll
  for (int k = 0; k < 4; ++k) {
    const int d = lane + k * 64;
    v[k] = xp[d] + rp[d];
    s += v[k];
  }
#pragma unroll
  for (int off = 32; off; off >>= 1) s += __shfl_xor(s, off, 64);
  const float mu = s * (1.f / 256.f);
  float var = 0.f;
#pragma unroll
  for (int k = 0; k < 4; ++k) { const float d = v[k] - mu; var += d * d; }
#pragma unroll
  for (int off = 32; off; off >>= 1) var += __shfl_xor(var, off, 64);
  const float rs = rsqrtf(var * (1.f / 256.f) + 1e-5f);
#pragma unroll
  for (int k = 0; k < 4; ++k) {
    const int d = lane + k * 64;
    Out[row * D_ + d] = (v[k] - mu) * rs * g[d] + bta[d];
  }
}

// ---------------------------------------------------------------------------
// out = clip(x @ W_vr.T + b_vr, 0, 1).  One thread per (row, j<33).
// ---------------------------------------------------------------------------
__global__ __launch_bounds__(256) void head_clip(
    const float* __restrict__ X, const float* __restrict__ Wv,
    const float* __restrict__ bv, float* __restrict__ Out) {
  const int gid = blockIdx.x * 256 + threadIdx.x;
  if (gid >= M_ * MOTION_) return;
  const int j = gid % MOTION_;
  const int row = gid / MOTION_;
  const float4* xr = reinterpret_cast<const float4*>(X + (size_t)row * D_);
  const float4* wr = reinterpret_cast<const float4*>(Wv + (size_t)j * D_);
  float acc = bv[j];
#pragma unroll
  for (int i = 0; i < 64; ++i) {
    const float4 a = xr[i], w = wr[i];
    acc += a.x * w.x + a.y * w.y + a.z * w.z + a.w * w.w;
  }
  Out[gid] = fminf(fmaxf(acc, 0.f), 1.f);
}

// ---------------------------------------------------------------------------
extern "C" void kernel_launch(void* const* d_in, const int* in_sizes, int n_in,
                              void* d_out, int out_size, void* d_ws, size_t ws_size,
                              hipStream_t stream) {
  (void)in_sizes; (void)n_in; (void)out_size; (void)ws_size;
  const float* hidden = (const float*)d_in[0];
  const float* tmot   = (const float*)d_in[1];
  const float* W_af   = (const float*)d_in[2];
  const float* b_af   = (const float*)d_in[3];
  const float* c1w    = (const float*)d_in[4];
  const float* c1b    = (const float*)d_in[5];
  const float* c2w    = (const float*)d_in[6];
  const float* c2b    = (const float*)d_in[7];
  const float* Wvm    = (const float*)d_in[8];
  const float* bvm    = (const float*)d_in[9];
  const float* sa_in_w  = (const float*)d_in[10];
  const float* sa_in_b  = (const float*)d_in[11];
  const float* sa_out_w = (const float*)d_in[12];
  const float* sa_out_b = (const float*)d_in[13];
  const float* ca_in_w  = (const float*)d_in[14];
  const float* ca_in_b  = (const float*)d_in[15];
  const float* ca_out_w = (const float*)d_in[16];
  const float* ca_out_b = (const float*)d_in[17];
  const float* ln1g = (const float*)d_in[18];
  const float* ln1b = (const float*)d_in[19];
  const float* ln2g = (const float*)d_in[20];
  const float* ln2b = (const float*)d_in[21];
  const float* ln3g = (const float*)d_in[22];
  const float* ln3b = (const float*)d_in[23];
  const float* ff1w = (const float*)d_in[24];
  const float* ff1b = (const float*)d_in[25];
  const float* ff2w = (const float*)d_in[26];
  const float* ff2b = (const float*)d_in[27];
  const float* Wvr  = (const float*)d_in[28];
  const float* bvr  = (const float*)d_in[29];
  float* out = (float*)d_out;

  float* ws = (float*)d_ws;
  const size_t BSD = (size_t)B_ * T_ * D_;  // 2,097,152 floats
  float* audio = ws;            // [B*S, 256]
  float* x     = ws + BSD;      // [B*T, 256]
  float* att   = ws + 2 * BSD;  // [B*T, 256]
  float* t1    = ws + 3 * BSD;  // [B*T, 256] scratch (also conv1 output)
  float* qkv   = ws + 4 * BSD;  // [B*T, 768] / reused for q, kv, ffn hidden

  const dim3 blk(256);

  // audio front-end
  gemm_bt<<<dim3(M_ / 64, D_ / 64), blk, 0, stream>>>(hidden, W_af, b_af, audio, M_, D_, AUDIO_, 0);
  conv5k<<<dim3(S_ / 64, D_ / 64, B_), blk, 0, stream>>>(audio, c1w, c1b, t1, 0);
  conv5k<<<dim3(S_ / 64, D_ / 64, B_), blk, 0, stream>>>(t1, c2w, c2b, audio, 1);

  // motion embedding + PE
  motion_pe<<<dim3(M_), blk, 0, stream>>>(tmot, Wvm, bvm, x);

  for (int l = 0; l < 2; ++l) {
    // self-attention
    gemm_bt<<<dim3(M_ / 64, 768 / 64), blk, 0, stream>>>(
        x, sa_in_w + (size_t)l * 768 * 256, sa_in_b + l * 768, qkv, M_, 768, 256, 0);
    self_attn<<<dim3(T_ / 64, H_, B_), blk, 0, stream>>>(qkv, att);
    gemm_bt<<<dim3(M_ / 64, 256 / 64), blk, 0, stream>>>(
        att, sa_out_w + (size_t)l * 256 * 256, sa_out_b + l * 256, t1, M_, 256, 256, 0);
    ln_res<<<dim3(M_ / 4), blk, 0, stream>>>(x, t1, ln1g + l * 256, ln1b + l * 256, x);

    // cross-attention (banded)
    gemm_bt<<<dim3(M_ / 64, 256 / 64), blk, 0, stream>>>(
        x, ca_in_w + (size_t)l * 768 * 256, ca_in_b + l * 768, qkv, M_, 256, 256, 0);
    gemm_bt<<<dim3(M_ / 64, 512 / 64), blk, 0, stream>>>(
        audio, ca_in_w + (size_t)l * 768 * 256 + 256 * 256, ca_in_b + l * 768 + 256,
        qkv + BSD, M_, 512, 256, 0);
    cross_attn<<<dim3(M_ * H_ / 256), blk, 0, stream>>>(qkv, qkv + BSD, att);
    gemm_bt<<<dim3(M_ / 64, 256 / 64), blk, 0, stream>>>(
        att, ca_out_w + (size_t)l * 256 * 256, ca_out_b + l * 256, t1, M_, 256, 256, 0);
    ln_res<<<dim3(M_ / 4), blk, 0, stream>>>(x, t1, ln2g + l * 256, ln2b + l * 256, x);

    // FFN
    gemm_bt<<<dim3(M_ / 64, 512 / 64), blk, 0, stream>>>(
        x, ff1w + (size_t)l * 512 * 256, ff1b + l * 512, qkv, M_, 512, 256, 1);
    gemm_bt<<<dim3(M_ / 64, 256 / 64), blk, 0, stream>>>(
        qkv, ff2w + (size_t)l * 256 * 512, ff2b + l * 256, t1, M_, 256, 512, 0);
    ln_res<<<dim3(M_ / 4), blk, 0, stream>>>(x, t1, ln3g + l * 256, ln3b + l * 256, x);
  }

  head_clip<<<dim3((M_ * MOTION_ + 255) / 256), blk, 0, stream>>>(x, Wvr, bvr, out);
}

// Round 4
// 967.091 us; speedup vs baseline: 2.3554x; 1.4212x over previous
//
#include <hip/hip_runtime.h>
#include <math.h>

#define B_ 8
#define T_ 1024
#define S_ 1024
#define D_ 256
#define H_ 4
#define DH_ 64
#define AUDIO_ 768
#define MOTION_ 33
#define PERIOD_ 30
#define WIN_ 4
#define M_ (B_ * T_)  // 8192 rows for [B*T, D]-shaped activations

typedef _Float16 half8 __attribute__((ext_vector_type(8)));  // 8 fp16 (4 VGPRs)
typedef __attribute__((ext_vector_type(4))) float f32x4;

// ---------------------------------------------------------------------------
// fp16-MFMA GEMM: C[m,n] = A[m,:] . W[n,:] + bias[n]  (optional ReLU)
// A: [M,K] fp32, W: [N,K] fp32. M%64==0, N%64==0, K%32==0.
// Block 256 thr = 4 waves (2x2), tile 64x64, BK=32, wave sub-tile 32x32.
// fp16 operands (10-bit mantissa) keep absmax under the 2e-2 budget where
// bf16 (7-bit) failed at 3.5e-2; accumulation is fp32 inside MFMA.
// ---------------------------------------------------------------------------
__global__ __launch_bounds__(256) void gemm_mfma(
    const float* __restrict__ A, const float* __restrict__ W,
    const float* __restrict__ bias, float* __restrict__ C,
    int M, int N, int K, int relu) {
  __shared__ _Float16 As[64][40];  // 40 = BK(32) + 8 pad (80 B row stride)
  __shared__ _Float16 Bs[64][40];
  const int tid = threadIdx.x;
  const int wave = tid >> 6, lane = tid & 63;
  const int wr = wave >> 1, wc = wave & 1;
  const int lr16 = lane & 15, kq = lane >> 4;  // frag row, k-quarter (8 each)
  const int bm = blockIdx.x, bn = blockIdx.y;

  const int sr = tid >> 2;          // staging row 0..63
  const int sq = tid & 3;           // staging k-quarter (8 floats)
  const float* Arow = A + (size_t)(bm * 64 + sr) * K + sq * 8;
  const float* Wrow = W + (size_t)(bn * 64 + sr) * K + sq * 8;

  f32x4 acc[2][2] = {};

  for (int k0 = 0; k0 < K; k0 += 32) {
    {
      const float4 a0 = *reinterpret_cast<const float4*>(Arow + k0);
      const float4 a1 = *reinterpret_cast<const float4*>(Arow + k0 + 4);
      half8 pa;
      pa[0] = (_Float16)a0.x; pa[1] = (_Float16)a0.y;
      pa[2] = (_Float16)a0.z; pa[3] = (_Float16)a0.w;
      pa[4] = (_Float16)a1.x; pa[5] = (_Float16)a1.y;
      pa[6] = (_Float16)a1.z; pa[7] = (_Float16)a1.w;
      *reinterpret_cast<half8*>(&As[sr][sq * 8]) = pa;
      const float4 w0 = *reinterpret_cast<const float4*>(Wrow + k0);
      const float4 w1 = *reinterpret_cast<const float4*>(Wrow + k0 + 4);
      half8 pw;
      pw[0] = (_Float16)w0.x; pw[1] = (_Float16)w0.y;
      pw[2] = (_Float16)w0.z; pw[3] = (_Float16)w0.w;
      pw[4] = (_Float16)w1.x; pw[5] = (_Float16)w1.y;
      pw[6] = (_Float16)w1.z; pw[7] = (_Float16)w1.w;
      *reinterpret_cast<half8*>(&Bs[sr][sq * 8]) = pw;
    }
    __syncthreads();
    half8 af[2], bf[2];
#pragma unroll
    for (int m = 0; m < 2; ++m)
      af[m] = *reinterpret_cast<const half8*>(&As[wr * 32 + m * 16 + lr16][kq * 8]);
#pragma unroll
    for (int n = 0; n < 2; ++n)
      bf[n] = *reinterpret_cast<const half8*>(&Bs[wc * 32 + n * 16 + lr16][kq * 8]);
#pragma unroll
    for (int m = 0; m < 2; ++m)
#pragma unroll
      for (int n = 0; n < 2; ++n)
        acc[m][n] = __builtin_amdgcn_mfma_f32_16x16x32_f16(af[m], bf[n], acc[m][n], 0, 0, 0);
    __syncthreads();
  }

  // epilogue: C/D layout col=lane&15, row=(lane>>4)*4+reg
#pragma unroll
  for (int m = 0; m < 2; ++m) {
#pragma unroll
    for (int n = 0; n < 2; ++n) {
      const int col = bn * 64 + wc * 32 + n * 16 + lr16;
      const float bv = bias[col];
#pragma unroll
      for (int j = 0; j < 4; ++j) {
        const int row = bm * 64 + wr * 32 + m * 16 + kq * 4 + j;
        float v = acc[m][n][j] + bv;
        if (relu) v = fmaxf(v, 0.f);
        C[(size_t)row * N + col] = v;
      }
    }
  }
}

// ---------------------------------------------------------------------------
// fp16-MFMA Conv1d k=5 pad=2 over [B,S,D] (channels innermost), as 40
// accumulated GEMM K-steps (5 taps x 8 c-blocks of 32).
// grid (M/64, D/64); batch = blockIdx.x>>4 (64 | 1024 so tiles never cross).
// mode 0: Y = gelu_exact(conv(X)+b);  mode 1: Y += conv(X)+b (residual).
// ---------------------------------------------------------------------------
__global__ __launch_bounds__(256) void conv_mfma(
    const float* __restrict__ X, const float* __restrict__ W,
    const float* __restrict__ bias, float* Y, int mode) {
  __shared__ _Float16 As[64][40];
  __shared__ _Float16 Bs[64][40];
  const int tid = threadIdx.x;
  const int wave = tid >> 6, lane = tid & 63;
  const int wr = wave >> 1, wc = wave & 1;
  const int lr16 = lane & 15, kq = lane >> 4;
  const int b = blockIdx.x >> 4;
  const int s0 = (blockIdx.x & 15) * 64;
  const int o0 = blockIdx.y * 64;

  const int sr = tid >> 2;   // staging row 0..63
  const int sq = tid & 3;    // 8-element quarter

  f32x4 acc[2][2] = {};

  for (int t = 0; t < 5; ++t) {
    for (int c0 = 0; c0 < D_; c0 += 32) {
      // A: X[b, s0+sr+t-2, c0+sq*8 ..+8]  (zero outside batch)
      {
        const int s = s0 + sr + t - 2;
        half8 pa = {};
        if (s >= 0 && s < S_) {
          const float* xp = X + ((size_t)b * S_ + s) * D_ + c0 + sq * 8;
          const float4 a0 = *reinterpret_cast<const float4*>(xp);
          const float4 a1 = *reinterpret_cast<const float4*>(xp + 4);
          pa[0] = (_Float16)a0.x; pa[1] = (_Float16)a0.y;
          pa[2] = (_Float16)a0.z; pa[3] = (_Float16)a0.w;
          pa[4] = (_Float16)a1.x; pa[5] = (_Float16)a1.y;
          pa[6] = (_Float16)a1.z; pa[7] = (_Float16)a1.w;
        }
        *reinterpret_cast<half8*>(&As[sr][sq * 8]) = pa;
      }
      // B: W[o0+sr, c0+sq*8+j, t]  (stride 5 in c)
      {
        const float* wp = W + ((size_t)(o0 + sr) * D_ + c0 + sq * 8) * 5 + t;
        half8 pw;
        pw[0] = (_Float16)wp[0];  pw[1] = (_Float16)wp[5];
        pw[2] = (_Float16)wp[10]; pw[3] = (_Float16)wp[15];
        pw[4] = (_Float16)wp[20]; pw[5] = (_Float16)wp[25];
        pw[6] = (_Float16)wp[30]; pw[7] = (_Float16)wp[35];
        *reinterpret_cast<half8*>(&Bs[sr][sq * 8]) = pw;
      }
      __syncthreads();
      half8 af[2], bf[2];
#pragma unroll
      for (int m = 0; m < 2; ++m)
        af[m] = *reinterpret_cast<const half8*>(&As[wr * 32 + m * 16 + lr16][kq * 8]);
#pragma unroll
      for (int n = 0; n < 2; ++n)
        bf[n] = *reinterpret_cast<const half8*>(&Bs[wc * 32 + n * 16 + lr16][kq * 8]);
#pragma unroll
      for (int m = 0; m < 2; ++m)
#pragma unroll
        for (int n = 0; n < 2; ++n)
          acc[m][n] = __builtin_amdgcn_mfma_f32_16x16x32_f16(af[m], bf[n], acc[m][n], 0, 0, 0);
      __syncthreads();
    }
  }

#pragma unroll
  for (int m = 0; m < 2; ++m) {
#pragma unroll
    for (int n = 0; n < 2; ++n) {
      const int oc = o0 + wc * 32 + n * 16 + lr16;
      const float bv = bias[oc];
#pragma unroll
      for (int j = 0; j < 4; ++j) {
        const int s = s0 + wr * 32 + m * 16 + kq * 4 + j;
        float* yp = Y + ((size_t)b * S_ + s) * D_ + oc;
        float v = acc[m][n][j] + bv;
        if (mode == 0) {
          v = 0.5f * v * (1.f + erff(v * 0.70710678118654752f));
          *yp = v;
        } else {
          *yp += v;
        }
      }
    }
  }
}

// ---------------------------------------------------------------------------
// x = shifted_motion @ W_vm.T + b_vm + PE(t%30)
// ---------------------------------------------------------------------------
__global__ __launch_bounds__(256) void motion_pe(
    const float* __restrict__ TM, const float* __restrict__ Wvm,
    const float* __restrict__ bvm, float* __restrict__ Xout) {
  const int d = threadIdx.x;
  const int bt = blockIdx.x;
  const int t = bt & (T_ - 1);
  const int b = bt >> 10;
  float acc = bvm[d];
  if (t > 0) {
    const float* mrow = TM + ((size_t)b * T_ + t - 1) * MOTION_;
    const float* wrow = Wvm + (size_t)d * MOTION_;
#pragma unroll
    for (int m = 0; m < MOTION_; ++m) acc += mrow[m] * wrow[m];
  }
  const int pos = t % PERIOD_;
  const int i2 = d >> 1;
  const float div = expf((float)(2 * i2) * (-9.210340371976184f / 256.f));
  const float ang = (float)pos * div;
  acc += (d & 1) ? cosf(ang) : sinf(ang);
  Xout[(size_t)bt * D_ + d] = acc;
}

// ---------------------------------------------------------------------------
// Self-attention, flash-decoding style (fp32).
// QKV: [B*T, 768] (q|k|v, each col = h*64+dh). Grid (T/64, H, B), 256 thr.
// 4 waves; causal key range split across waves in 32-key slices from a
// 128-key LDS round. Per-wave online softmax, merged through LDS.
// score = q.k/8 - slope_h * ((t-s)/30)  for s<=t else -inf; slope_h=0.25^(h+1)
// ---------------------------------------------------------------------------
__global__ __launch_bounds__(256) void self_attn(
    const float* __restrict__ QKV, float* __restrict__ O) {
  __shared__ float smem[256 * 68];   // K rows 0..127, V rows 128..255 (stride 68)
  __shared__ float Mp[4][64], Lp[4][64];
  const int qt = blockIdx.x;
  const int h = blockIdx.y;
  const int b = blockIdx.z;
  const int tid = threadIdx.x;
  const int wave = tid >> 6, lane = tid & 63;
  const int t = qt * 64 + lane;
  const float slope = exp2f(-2.f * (float)(h + 1));
  const size_t qkbase = ((size_t)b * T_) * 768 + h * 64;

  for (int idx = tid; idx < 64 * 16; idx += 256) {
    const int r = idx >> 4, c4 = (idx & 15) << 2;
    *reinterpret_cast<float4*>(&smem[r * 68 + c4]) =
        *reinterpret_cast<const float4*>(QKV + qkbase + (size_t)(qt * 64 + r) * 768 + c4);
  }
  __syncthreads();
  float q[64];
#pragma unroll
  for (int d0 = 0; d0 < 64; d0 += 4) {
    const float4 v = *reinterpret_cast<const float4*>(&smem[lane * 68 + d0]);
    q[d0] = v.x; q[d0 + 1] = v.y; q[d0 + 2] = v.z; q[d0 + 3] = v.w;
  }
  __syncthreads();

  float o[64];
#pragma unroll
  for (int d = 0; d < 64; ++d) o[d] = 0.f;
  float mrun = -1e30f, lrun = 0.f;

  const int nkey = (qt + 1) * 64;
  for (int k0 = 0; k0 < nkey; k0 += 128) {
    const int cnt = min(128, nkey - k0);
    for (int idx = tid; idx < cnt * 16; idx += 256) {
      const int r = idx >> 4, c4 = (idx & 15) << 2;
      const size_t rowoff = qkbase + (size_t)(k0 + r) * 768;
      *reinterpret_cast<float4*>(&smem[r * 68 + c4]) =
          *reinterpret_cast<const float4*>(QKV + rowoff + 256 + c4);
      *reinterpret_cast<float4*>(&smem[(128 + r) * 68 + c4]) =
          *reinterpret_cast<const float4*>(QKV + rowoff + 512 + c4);
    }
    __syncthreads();

    const int kw0 = wave * 32;
    if (kw0 < cnt) {
      for (int jt = 0; jt < 32; jt += 16) {
        float p[16];
        float tmax = -1e30f;
#pragma unroll
        for (int jj = 0; jj < 16; ++jj) {
          const int r = kw0 + jt + jj;
          float sc = 0.f;
#pragma unroll
          for (int d0 = 0; d0 < 64; d0 += 4) {
            const float4 kv = *reinterpret_cast<const float4*>(&smem[r * 68 + d0]);
            sc += q[d0] * kv.x + q[d0 + 1] * kv.y + q[d0 + 2] * kv.z + q[d0 + 3] * kv.w;
          }
          const int rel = t - (k0 + r);
          sc = (rel >= 0) ? sc * 0.125f - slope * (float)(rel / PERIOD_) : -1e30f;
          p[jj] = sc;
          tmax = fmaxf(tmax, sc);
        }
        const float mnew = fmaxf(mrun, tmax);
        const float scale = __expf(mrun - mnew);
        lrun *= scale;
#pragma unroll
        for (int d = 0; d < 64; ++d) o[d] *= scale;
#pragma unroll
        for (int jj = 0; jj < 16; ++jj) {
          const int r = 128 + kw0 + jt + jj;
          const float pj = __expf(p[jj] - mnew);
          lrun += pj;
#pragma unroll
          for (int d0 = 0; d0 < 64; d0 += 4) {
            const float4 vv = *reinterpret_cast<const float4*>(&smem[r * 68 + d0]);
            o[d0] += pj * vv.x; o[d0 + 1] += pj * vv.y;
            o[d0 + 2] += pj * vv.z; o[d0 + 3] += pj * vv.w;
          }
        }
        mrun = mnew;
      }
    }
    __syncthreads();
  }

  {
    float* orow = &smem[(wave * 64 + lane) * 68];
#pragma unroll
    for (int d0 = 0; d0 < 64; d0 += 4) {
      float4 v; v.x = o[d0]; v.y = o[d0 + 1]; v.z = o[d0 + 2]; v.w = o[d0 + 3];
      *reinterpret_cast<float4*>(&orow[d0]) = v;
    }
    Mp[wave][lane] = mrun;
    Lp[wave][lane] = lrun;
  }
  __syncthreads();

  const int qq = tid & 63, part = tid >> 6;
  const float m = fmaxf(fmaxf(Mp[0][qq], Mp[1][qq]), fmaxf(Mp[2][qq], Mp[3][qq]));
  const float s0 = __expf(Mp[0][qq] - m);
  const float s1 = __expf(Mp[1][qq] - m);
  const float s2 = __expf(Mp[2][qq] - m);
  const float s3 = __expf(Mp[3][qq] - m);
  const float l = Lp[0][qq] * s0 + Lp[1][qq] * s1 + Lp[2][qq] * s2 + Lp[3][qq] * s3;
  const float inv = 1.f / l;
  float* op = O + ((size_t)b * T_ + qt * 64 + qq) * D_ + h * 64 + part * 16;
#pragma unroll
  for (int d0 = 0; d0 < 16; d0 += 4) {
    const int c = part * 16 + d0;
    const float4 a0 = *reinterpret_cast<const float4*>(&smem[(0 * 64 + qq) * 68 + c]);
    const float4 a1 = *reinterpret_cast<const float4*>(&smem[(1 * 64 + qq) * 68 + c]);
    const float4 a2 = *reinterpret_cast<const float4*>(&smem[(2 * 64 + qq) * 68 + c]);
    const float4 a3 = *reinterpret_cast<const float4*>(&smem[(3 * 64 + qq) * 68 + c]);
    float4 r;
    r.x = (a0.x * s0 + a1.x * s1 + a2.x * s2 + a3.x * s3) * inv;
    r.y = (a0.y * s0 + a1.y * s1 + a2.y * s2 + a3.y * s3) * inv;
    r.z = (a0.z * s0 + a1.z * s1 + a2.z * s2 + a3.z * s3) * inv;
    r.w = (a0.w * s0 + a1.w * s1 + a2.w * s2 + a3.w * s3) * inv;
    *reinterpret_cast<float4*>(op + d0) = r;
  }
}

// ---------------------------------------------------------------------------
// Cross-attention with band mask |t-j|<=4. Q: [B*T,256], KV: [B*S,512] (k|v).
// One thread per (b,t,h); at most 9 keys, softmax fully in registers.
// ---------------------------------------------------------------------------
__global__ __launch_bounds__(256) void cross_attn(
    const float* __restrict__ Q, const float* __restrict__ KV,
    float* __restrict__ O) {
  const int gid = blockIdx.x * 256 + threadIdx.x;  // 0 .. B*T*H-1
  const int h = gid & 3;
  const int bt = gid >> 2;
  const int t = bt & (T_ - 1);
  const int b = bt >> 10;

  float q[64];
  const float* qp = Q + (size_t)bt * D_ + h * 64;
#pragma unroll
  for (int d0 = 0; d0 < 64; d0 += 4) {
    const float4 v = *reinterpret_cast<const float4*>(qp + d0);
    q[d0] = v.x; q[d0 + 1] = v.y; q[d0 + 2] = v.z; q[d0 + 3] = v.w;
  }

  const int j0 = (t - WIN_ > 0) ? t - WIN_ : 0;
  const int j1 = (t + WIN_ < S_ - 1) ? t + WIN_ : S_ - 1;
  const int nj = j1 - j0 + 1;

  float sc[9];
  float mx = -1e30f;
#pragma unroll
  for (int jj = 0; jj < 9; ++jj) {
    if (jj < nj) {
      const float* kp = KV + ((size_t)b * S_ + j0 + jj) * 512 + h * 64;
      float s = 0.f;
#pragma unroll
      for (int d0 = 0; d0 < 64; d0 += 4) {
        const float4 kv = *reinterpret_cast<const float4*>(kp + d0);
        s += q[d0] * kv.x + q[d0 + 1] * kv.y + q[d0 + 2] * kv.z + q[d0 + 3] * kv.w;
      }
      sc[jj] = s * 0.125f;
      mx = fmaxf(mx, sc[jj]);
    } else {
      sc[jj] = -1e30f;
    }
  }
  float l = 0.f;
  float p[9];
#pragma unroll
  for (int jj = 0; jj < 9; ++jj) { p[jj] = __expf(sc[jj] - mx); l += p[jj]; }
  const float inv = 1.f / l;

  float o[64];
#pragma unroll
  for (int d = 0; d < 64; ++d) o[d] = 0.f;
#pragma unroll
  for (int jj = 0; jj < 9; ++jj) {
    if (jj < nj) {
      const float pj = p[jj] * inv;
      const float* vp = KV + ((size_t)b * S_ + j0 + jj) * 512 + 256 + h * 64;
#pragma unroll
      for (int d0 = 0; d0 < 64; d0 += 4) {
        const float4 vv = *reinterpret_cast<const float4*>(vp + d0);
        o[d0] += pj * vv.x; o[d0 + 1] += pj * vv.y;
        o[d0 + 2] += pj * vv.z; o[d0 + 3] += pj * vv.w;
      }
    }
  }
  float* op = O + (size_t)bt * D_ + h * 64;
#pragma unroll
  for (int d = 0; d < 64; ++d) op[d] = o[d];
}

// ---------------------------------------------------------------------------
// Out = LayerNorm(X + R) * g + b.   One wave per 256-wide row. Out may == X.
// ---------------------------------------------------------------------------
__global__ __launch_bounds__(256) void ln_res(
    const float* X, const float* __restrict__ R,
    const float* __restrict__ g, const float* __restrict__ bta, float* Out) {
  const int wid = threadIdx.x >> 6, lane = threadIdx.x & 63;
  const size_t row = (size_t)blockIdx.x * 4 + wid;
  const float* xp = X + row * D_;
  const float* rp = R + row * D_;
  float v[4];
  float s = 0.f;
#pragma unroll
  for (int k = 0; k < 4; ++k) {
    const int d = lane + k * 64;
    v[k] = xp[d] + rp[d];
    s += v[k];
  }
#pragma unroll
  for (int off = 32; off; off >>= 1) s += __shfl_xor(s, off, 64);
  const float mu = s * (1.f / 256.f);
  float var = 0.f;
#pragma unroll
  for (int k = 0; k < 4; ++k) { const float d = v[k] - mu; var += d * d; }
#pragma unroll
  for (int off = 32; off; off >>= 1) var += __shfl_xor(var, off, 64);
  const float rs = rsqrtf(var * (1.f / 256.f) + 1e-5f);
#pragma unroll
  for (int k = 0; k < 4; ++k) {
    const int d = lane + k * 64;
    Out[row * D_ + d] = (v[k] - mu) * rs * g[d] + bta[d];
  }
}

// ---------------------------------------------------------------------------
// out = clip(x @ W_vr.T + b_vr, 0, 1).  One thread per (row, j<33).
// ---------------------------------------------------------------------------
__global__ __launch_bounds__(256) void head_clip(
    const float* __restrict__ X, const float* __restrict__ Wv,
    const float* __restrict__ bv, float* __restrict__ Out) {
  const int gid = blockIdx.x * 256 + threadIdx.x;
  if (gid >= M_ * MOTION_) return;
  const int j = gid % MOTION_;
  const int row = gid / MOTION_;
  const float4* xr = reinterpret_cast<const float4*>(X + (size_t)row * D_);
  const float4* wr = reinterpret_cast<const float4*>(Wv + (size_t)j * D_);
  float acc = bv[j];
#pragma unroll
  for (int i = 0; i < 64; ++i) {
    const float4 a = xr[i], w = wr[i];
    acc += a.x * w.x + a.y * w.y + a.z * w.z + a.w * w.w;
  }
  Out[gid] = fminf(fmaxf(acc, 0.f), 1.f);
}

// ---------------------------------------------------------------------------
extern "C" void kernel_launch(void* const* d_in, const int* in_sizes, int n_in,
                              void* d_out, int out_size, void* d_ws, size_t ws_size,
                              hipStream_t stream) {
  (void)in_sizes; (void)n_in; (void)out_size; (void)ws_size;
  const float* hidden = (const float*)d_in[0];
  const float* tmot   = (const float*)d_in[1];
  const float* W_af   = (const float*)d_in[2];
  const float* b_af   = (const float*)d_in[3];
  const float* c1w    = (const float*)d_in[4];
  const float* c1b    = (const float*)d_in[5];
  const float* c2w    = (const float*)d_in[6];
  const float* c2b    = (const float*)d_in[7];
  const float* Wvm    = (const float*)d_in[8];
  const float* bvm    = (const float*)d_in[9];
  const float* sa_in_w  = (const float*)d_in[10];
  const float* sa_in_b  = (const float*)d_in[11];
  const float* sa_out_w = (const float*)d_in[12];
  const float* sa_out_b = (const float*)d_in[13];
  const float* ca_in_w  = (const float*)d_in[14];
  const float* ca_in_b  = (const float*)d_in[15];
  const float* ca_out_w = (const float*)d_in[16];
  const float* ca_out_b = (const float*)d_in[17];
  const float* ln1g = (const float*)d_in[18];
  const float* ln1b = (const float*)d_in[19];
  const float* ln2g = (const float*)d_in[20];
  const float* ln2b = (const float*)d_in[21];
  const float* ln3g = (const float*)d_in[22];
  const float* ln3b = (const float*)d_in[23];
  const float* ff1w = (const float*)d_in[24];
  const float* ff1b = (const float*)d_in[25];
  const float* ff2w = (const float*)d_in[26];
  const float* ff2b = (const float*)d_in[27];
  const float* Wvr  = (const float*)d_in[28];
  const float* bvr  = (const float*)d_in[29];
  float* out = (float*)d_out;

  float* ws = (float*)d_ws;
  const size_t BSD = (size_t)B_ * T_ * D_;  // 2,097,152 floats
  float* audio = ws;            // [B*S, 256]
  float* x     = ws + BSD;      // [B*T, 256]
  float* att   = ws + 2 * BSD;  // [B*T, 256]
  float* t1    = ws + 3 * BSD;  // [B*T, 256] scratch (conv1 output)
  float* qkv   = ws + 4 * BSD;  // [B*T, 768] / reused for q, kv, ffn hidden

  const dim3 blk(256);

  // audio front-end
  gemm_mfma<<<dim3(M_ / 64, D_ / 64), blk, 0, stream>>>(hidden, W_af, b_af, audio, M_, D_, AUDIO_, 0);
  conv_mfma<<<dim3(M_ / 64, D_ / 64), blk, 0, stream>>>(audio, c1w, c1b, t1, 0);
  conv_mfma<<<dim3(M_ / 64, D_ / 64), blk, 0, stream>>>(t1, c2w, c2b, audio, 1);

  // motion embedding + PE
  motion_pe<<<dim3(M_), blk, 0, stream>>>(tmot, Wvm, bvm, x);

  for (int l = 0; l < 2; ++l) {
    // self-attention
    gemm_mfma<<<dim3(M_ / 64, 768 / 64), blk, 0, stream>>>(
        x, sa_in_w + (size_t)l * 768 * 256, sa_in_b + l * 768, qkv, M_, 768, 256, 0);
    self_attn<<<dim3(T_ / 64, H_, B_), blk, 0, stream>>>(qkv, att);
    gemm_mfma<<<dim3(M_ / 64, 256 / 64), blk, 0, stream>>>(
        att, sa_out_w + (size_t)l * 256 * 256, sa_out_b + l * 256, t1, M_, 256, 256, 0);
    ln_res<<<dim3(M_ / 4), blk, 0, stream>>>(x, t1, ln1g + l * 256, ln1b + l * 256, x);

    // cross-attention (banded)
    gemm_mfma<<<dim3(M_ / 64, 256 / 64), blk, 0, stream>>>(
        x, ca_in_w + (size_t)l * 768 * 256, ca_in_b + l * 768, qkv, M_, 256, 256, 0);
    gemm_mfma<<<dim3(M_ / 64, 512 / 64), blk, 0, stream>>>(
        audio, ca_in_w + (size_t)l * 768 * 256 + 256 * 256, ca_in_b + l * 768 + 256,
        qkv + BSD, M_, 512, 256, 0);
    cross_attn<<<dim3(M_ * H_ / 256), blk, 0, stream>>>(qkv, qkv + BSD, att);
    gemm_mfma<<<dim3(M_ / 64, 256 / 64), blk, 0, stream>>>(
        att, ca_out_w + (size_t)l * 256 * 256, ca_out_b + l * 256, t1, M_, 256, 256, 0);
    ln_res<<<dim3(M_ / 4), blk, 0, stream>>>(x, t1, ln2g + l * 256, ln2b + l * 256, x);

    // FFN
    gemm_mfma<<<dim3(M_ / 64, 512 / 64), blk, 0, stream>>>(
        x, ff1w + (size_t)l * 512 * 256, ff1b + l * 512, qkv, M_, 512, 256, 1);
    gemm_mfma<<<dim3(M_ / 64, 256 / 64), blk, 0, stream>>>(
        qkv, ff2w + (size_t)l * 256 * 512, ff2b + l * 256, t1, M_, 256, 512, 0);
    ln_res<<<dim3(M_ / 4), blk, 0, stream>>>(x, t1, ln3g + l * 256, ln3b + l * 256, x);
  }

  head_clip<<<dim3((M_ * MOTION_ + 255) / 256), blk, 0, stream>>>(x, Wvr, bvr, out);
}

// Round 5
// 616.864 us; speedup vs baseline: 3.6927x; 1.5678x over previous
//
#include <hip/hip_runtime.h>
#include <math.h>

#define B_ 8
#define T_ 1024
#define S_ 1024
#define D_ 256
#define H_ 4
#define DH_ 64
#define AUDIO_ 768
#define MOTION_ 33
#define PERIOD_ 30
#define WIN_ 4
#define M_ (B_ * T_)  // 8192 rows for [B*T, D]-shaped activations

typedef _Float16 half8 __attribute__((ext_vector_type(8)));  // 8 fp16 (4 VGPRs)
typedef _Float16 half4 __attribute__((ext_vector_type(4)));
typedef __attribute__((ext_vector_type(4))) float f32x4;

// ---------------------------------------------------------------------------
// fp16-MFMA GEMM: C[m,n] = A[m,:] . W[n,:] + bias[n]  (optional ReLU)
// A: [M,K] fp32, W: [N,K] fp32. M%64==0, N%64==0, K%32==0.
// Block 256 thr = 4 waves (2x2), tile 64x64, BK=32, wave sub-tile 32x32.
// ---------------------------------------------------------------------------
__global__ __launch_bounds__(256) void gemm_mfma(
    const float* __restrict__ A, const float* __restrict__ W,
    const float* __restrict__ bias, float* __restrict__ C,
    int M, int N, int K, int relu) {
  __shared__ _Float16 As[64][40];  // 40 = BK(32) + 8 pad (80 B row stride)
  __shared__ _Float16 Bs[64][40];
  const int tid = threadIdx.x;
  const int wave = tid >> 6, lane = tid & 63;
  const int wr = wave >> 1, wc = wave & 1;
  const int lr16 = lane & 15, kq = lane >> 4;  // frag row, k-quarter (8 each)
  const int bm = blockIdx.x, bn = blockIdx.y;

  const int sr = tid >> 2;          // staging row 0..63
  const int sq = tid & 3;           // staging k-quarter (8 floats)
  const float* Arow = A + (size_t)(bm * 64 + sr) * K + sq * 8;
  const float* Wrow = W + (size_t)(bn * 64 + sr) * K + sq * 8;

  f32x4 acc[2][2] = {};

  for (int k0 = 0; k0 < K; k0 += 32) {
    {
      const float4 a0 = *reinterpret_cast<const float4*>(Arow + k0);
      const float4 a1 = *reinterpret_cast<const float4*>(Arow + k0 + 4);
      half8 pa;
      pa[0] = (_Float16)a0.x; pa[1] = (_Float16)a0.y;
      pa[2] = (_Float16)a0.z; pa[3] = (_Float16)a0.w;
      pa[4] = (_Float16)a1.x; pa[5] = (_Float16)a1.y;
      pa[6] = (_Float16)a1.z; pa[7] = (_Float16)a1.w;
      *reinterpret_cast<half8*>(&As[sr][sq * 8]) = pa;
      const float4 w0 = *reinterpret_cast<const float4*>(Wrow + k0);
      const float4 w1 = *reinterpret_cast<const float4*>(Wrow + k0 + 4);
      half8 pw;
      pw[0] = (_Float16)w0.x; pw[1] = (_Float16)w0.y;
      pw[2] = (_Float16)w0.z; pw[3] = (_Float16)w0.w;
      pw[4] = (_Float16)w1.x; pw[5] = (_Float16)w1.y;
      pw[6] = (_Float16)w1.z; pw[7] = (_Float16)w1.w;
      *reinterpret_cast<half8*>(&Bs[sr][sq * 8]) = pw;
    }
    __syncthreads();
    half8 af[2], bf[2];
#pragma unroll
    for (int m = 0; m < 2; ++m)
      af[m] = *reinterpret_cast<const half8*>(&As[wr * 32 + m * 16 + lr16][kq * 8]);
#pragma unroll
    for (int n = 0; n < 2; ++n)
      bf[n] = *reinterpret_cast<const half8*>(&Bs[wc * 32 + n * 16 + lr16][kq * 8]);
#pragma unroll
    for (int m = 0; m < 2; ++m)
#pragma unroll
      for (int n = 0; n < 2; ++n)
        acc[m][n] = __builtin_amdgcn_mfma_f32_16x16x32_f16(af[m], bf[n], acc[m][n], 0, 0, 0);
    __syncthreads();
  }

  // epilogue: C/D layout col=lane&15, row=(lane>>4)*4+reg
#pragma unroll
  for (int m = 0; m < 2; ++m) {
#pragma unroll
    for (int n = 0; n < 2; ++n) {
      const int col = bn * 64 + wc * 32 + n * 16 + lr16;
      const float bv = bias[col];
#pragma unroll
      for (int j = 0; j < 4; ++j) {
        const int row = bm * 64 + wr * 32 + m * 16 + kq * 4 + j;
        float v = acc[m][n][j] + bv;
        if (relu) v = fmaxf(v, 0.f);
        C[(size_t)row * N + col] = v;
      }
    }
  }
}

// ---------------------------------------------------------------------------
// fp16-MFMA Conv1d k=5 pad=2 over [B,S,D] (channels innermost), as 40
// accumulated GEMM K-steps (5 taps x 8 c-blocks of 32).
// grid (M/64, D/64); batch = blockIdx.x>>4 (64 | 1024 so tiles never cross).
// mode 0: Y = gelu_exact(conv(X)+b);  mode 1: Y += conv(X)+b (residual).
// ---------------------------------------------------------------------------
__global__ __launch_bounds__(256) void conv_mfma(
    const float* __restrict__ X, const float* __restrict__ W,
    const float* __restrict__ bias, float* Y, int mode) {
  __shared__ _Float16 As[64][40];
  __shared__ _Float16 Bs[64][40];
  const int tid = threadIdx.x;
  const int wave = tid >> 6, lane = tid & 63;
  const int wr = wave >> 1, wc = wave & 1;
  const int lr16 = lane & 15, kq = lane >> 4;
  const int b = blockIdx.x >> 4;
  const int s0 = (blockIdx.x & 15) * 64;
  const int o0 = blockIdx.y * 64;

  const int sr = tid >> 2;   // staging row 0..63
  const int sq = tid & 3;    // 8-element quarter

  f32x4 acc[2][2] = {};

  for (int t = 0; t < 5; ++t) {
    for (int c0 = 0; c0 < D_; c0 += 32) {
      {
        const int s = s0 + sr + t - 2;
        half8 pa = {};
        if (s >= 0 && s < S_) {
          const float* xp = X + ((size_t)b * S_ + s) * D_ + c0 + sq * 8;
          const float4 a0 = *reinterpret_cast<const float4*>(xp);
          const float4 a1 = *reinterpret_cast<const float4*>(xp + 4);
          pa[0] = (_Float16)a0.x; pa[1] = (_Float16)a0.y;
          pa[2] = (_Float16)a0.z; pa[3] = (_Float16)a0.w;
          pa[4] = (_Float16)a1.x; pa[5] = (_Float16)a1.y;
          pa[6] = (_Float16)a1.z; pa[7] = (_Float16)a1.w;
        }
        *reinterpret_cast<half8*>(&As[sr][sq * 8]) = pa;
      }
      {
        const float* wp = W + ((size_t)(o0 + sr) * D_ + c0 + sq * 8) * 5 + t;
        half8 pw;
        pw[0] = (_Float16)wp[0];  pw[1] = (_Float16)wp[5];
        pw[2] = (_Float16)wp[10]; pw[3] = (_Float16)wp[15];
        pw[4] = (_Float16)wp[20]; pw[5] = (_Float16)wp[25];
        pw[6] = (_Float16)wp[30]; pw[7] = (_Float16)wp[35];
        *reinterpret_cast<half8*>(&Bs[sr][sq * 8]) = pw;
      }
      __syncthreads();
      half8 af[2], bf[2];
#pragma unroll
      for (int m = 0; m < 2; ++m)
        af[m] = *reinterpret_cast<const half8*>(&As[wr * 32 + m * 16 + lr16][kq * 8]);
#pragma unroll
      for (int n = 0; n < 2; ++n)
        bf[n] = *reinterpret_cast<const half8*>(&Bs[wc * 32 + n * 16 + lr16][kq * 8]);
#pragma unroll
      for (int m = 0; m < 2; ++m)
#pragma unroll
        for (int n = 0; n < 2; ++n)
          acc[m][n] = __builtin_amdgcn_mfma_f32_16x16x32_f16(af[m], bf[n], acc[m][n], 0, 0, 0);
      __syncthreads();
    }
  }

#pragma unroll
  for (int m = 0; m < 2; ++m) {
#pragma unroll
    for (int n = 0; n < 2; ++n) {
      const int oc = o0 + wc * 32 + n * 16 + lr16;
      const float bv = bias[oc];
#pragma unroll
      for (int j = 0; j < 4; ++j) {
        const int s = s0 + wr * 32 + m * 16 + kq * 4 + j;
        float* yp = Y + ((size_t)b * S_ + s) * D_ + oc;
        float v = acc[m][n][j] + bv;
        if (mode == 0) {
          v = 0.5f * v * (1.f + erff(v * 0.70710678118654752f));
          *yp = v;
        } else {
          *yp += v;
        }
      }
    }
  }
}

// ---------------------------------------------------------------------------
// x = shifted_motion @ W_vm.T + b_vm + PE(t%30)
// ---------------------------------------------------------------------------
__global__ __launch_bounds__(256) void motion_pe(
    const float* __restrict__ TM, const float* __restrict__ Wvm,
    const float* __restrict__ bvm, float* __restrict__ Xout) {
  const int d = threadIdx.x;
  const int bt = blockIdx.x;
  const int t = bt & (T_ - 1);
  const int b = bt >> 10;
  float acc = bvm[d];
  if (t > 0) {
    const float* mrow = TM + ((size_t)b * T_ + t - 1) * MOTION_;
    const float* wrow = Wvm + (size_t)d * MOTION_;
#pragma unroll
    for (int m = 0; m < MOTION_; ++m) acc += mrow[m] * wrow[m];
  }
  const int pos = t % PERIOD_;
  const int i2 = d >> 1;
  const float div = expf((float)(2 * i2) * (-9.210340371976184f / 256.f));
  const float ang = (float)pos * div;
  acc += (d & 1) ? cosf(ang) : sinf(ang);
  Xout[(size_t)bt * D_ + d] = acc;
}

// ---------------------------------------------------------------------------
// MFMA self-attention (fp16 operands, fp32 accum), swapped-QK^T layout.
// QKV: [B*T, 768] (q|k|v, col = h*64+dh). Grid (T/64, H, B), 256 thr / 4 waves.
// Wave w owns queries w*16..w*16+16 of the 64-query tile; loops causal key
// tiles of 64. S^T = mfma(K,Q) puts each query's scores in one lane column:
// softmax reduce = 15 local fmax + 2 shfl_xor. P round-trips through a
// per-wave LDS buffer to reach MFMA A-layout; O += mfma(P, V^T).
// V^T staged with XOR swizzle j^=((d&7)^(d>>3))<<3 (bank-spread writes,
// b128-contiguous reads). score = qk/8 - slope*((t-s)/30), causal.
// ---------------------------------------------------------------------------
#define RS_ 72  // fp16 row stride (64 + 8 pad), 144 B
__global__ __launch_bounds__(256) void self_attn(
    const float* __restrict__ QKV, float* __restrict__ O) {
  __shared__ _Float16 Ks[64 * RS_];
  __shared__ _Float16 VTs[64 * RS_];
  __shared__ _Float16 Ps[4][16 * RS_];
  const int qt = blockIdx.x, h = blockIdx.y, b = blockIdx.z;
  const int tid = threadIdx.x;
  const int wave = tid >> 6, lane = tid & 63;
  const int lo = lane & 15, hi = lane >> 4;
  const float slope = exp2f(-2.f * (float)(h + 1));
  const int qloc = wave * 16 + lo;      // query within 64-tile (softmax lane)
  const int tq = qt * 64 + qloc;        // absolute query index
  const size_t base = (size_t)b * T_ * 768 + h * 64;

  // Q fragments (B-operand): lane holds q=qloc, k = s*32 + hi*8 + e
  half8 qf[2];
#pragma unroll
  for (int s = 0; s < 2; ++s) {
    const float* qp = QKV + base + (size_t)(qt * 64 + qloc) * 768 + s * 32 + hi * 8;
    const float4 q0 = *reinterpret_cast<const float4*>(qp);
    const float4 q1 = *reinterpret_cast<const float4*>(qp + 4);
    qf[s][0] = (_Float16)q0.x; qf[s][1] = (_Float16)q0.y;
    qf[s][2] = (_Float16)q0.z; qf[s][3] = (_Float16)q0.w;
    qf[s][4] = (_Float16)q1.x; qf[s][5] = (_Float16)q1.y;
    qf[s][6] = (_Float16)q1.z; qf[s][7] = (_Float16)q1.w;
  }

  f32x4 oacc[4] = {};
  float mrun = -1e30f, lrun = 0.f;

  for (int kt = 0; kt <= qt; ++kt) {
    __syncthreads();  // previous tile fully consumed before restage
    // stage K [j][dh] and V^T [d][j^sw]
    for (int c = tid; c < 512; c += 256) {
      const int j = c >> 3, ch = c & 7;
      const size_t rowoff = base + (size_t)(kt * 64 + j) * 768;
      {
        const float* kp = QKV + rowoff + 256 + ch * 8;
        const float4 k0 = *reinterpret_cast<const float4*>(kp);
        const float4 k1 = *reinterpret_cast<const float4*>(kp + 4);
        half8 hk;
        hk[0] = (_Float16)k0.x; hk[1] = (_Float16)k0.y;
        hk[2] = (_Float16)k0.z; hk[3] = (_Float16)k0.w;
        hk[4] = (_Float16)k1.x; hk[5] = (_Float16)k1.y;
        hk[6] = (_Float16)k1.z; hk[7] = (_Float16)k1.w;
        *reinterpret_cast<half8*>(&Ks[j * RS_ + ch * 8]) = hk;
      }
      {
        const float* vp = QKV + rowoff + 512 + ch * 8;
        const float4 v0 = *reinterpret_cast<const float4*>(vp);
        const float4 v1 = *reinterpret_cast<const float4*>(vp + 4);
        float vv[8] = {v0.x, v0.y, v0.z, v0.w, v1.x, v1.y, v1.z, v1.w};
#pragma unroll
        for (int r = 0; r < 8; ++r) {
          const int d = ch * 8 + r;
          const int sw = ((d & 7) ^ (d >> 3)) << 3;
          VTs[d * RS_ + (j ^ sw)] = (_Float16)vv[r];
        }
      }
    }
    __syncthreads();

    // S^T = mfma(K, Q): col = query (lo), row = key (hi*4+r) per 16-frag
    f32x4 st[4] = {};
#pragma unroll
    for (int f = 0; f < 4; ++f) {
#pragma unroll
      for (int s = 0; s < 2; ++s) {
        const half8 kf = *reinterpret_cast<const half8*>(
            &Ks[(f * 16 + lo) * RS_ + s * 32 + hi * 8]);
        st[f] = __builtin_amdgcn_mfma_f32_16x16x32_f16(kf, qf[s], st[f], 0, 0, 0);
      }
    }

    // mask + ALiBi, tile max over this lane's 16 keys + 2 shfl_xor
    float sc[4][4];
    float tmax = -1e30f;
#pragma unroll
    for (int f = 0; f < 4; ++f)
#pragma unroll
      for (int r = 0; r < 4; ++r) {
        const int j = kt * 64 + f * 16 + hi * 4 + r;
        const int rel = tq - j;
        const float v = (rel >= 0)
            ? st[f][r] * 0.125f - slope * (float)(rel / PERIOD_) : -1e30f;
        sc[f][r] = v;
        tmax = fmaxf(tmax, v);
      }
    tmax = fmaxf(tmax, __shfl_xor(tmax, 16, 64));
    tmax = fmaxf(tmax, __shfl_xor(tmax, 32, 64));
    const float mnew = fmaxf(mrun, tmax);
    const float scale = __expf(mrun - mnew);

    // p = exp(sc - mnew); write per-wave P (A-layout rows = query)
    float psum = 0.f;
#pragma unroll
    for (int f = 0; f < 4; ++f) {
      half4 ph;
#pragma unroll
      for (int r = 0; r < 4; ++r) {
        const float p = __expf(sc[f][r] - mnew);
        psum += p;
        ph[r] = (_Float16)p;
      }
      *reinterpret_cast<half4*>(&Ps[wave][lo * RS_ + f * 16 + hi * 4]) = ph;
    }
    psum += __shfl_xor(psum, 16, 64);
    psum += __shfl_xor(psum, 32, 64);
    lrun = lrun * scale + psum;
    mrun = mnew;

    // rescale O: row q2 = hi*4+r needs scale from lane q2 (lo==q2, hi=0)
    float rsc[4];
#pragma unroll
    for (int r = 0; r < 4; ++r) rsc[r] = __shfl(scale, hi * 4 + r, 64);
#pragma unroll
    for (int nf = 0; nf < 4; ++nf)
#pragma unroll
      for (int r = 0; r < 4; ++r) oacc[nf][r] *= rsc[r];

    // O += P @ V^T  (A rows = query, B cols = d)
#pragma unroll
    for (int s = 0; s < 2; ++s) {
      const half8 pf = *reinterpret_cast<const half8*>(
          &Ps[wave][lo * RS_ + s * 32 + hi * 8]);
#pragma unroll
      for (int nf = 0; nf < 4; ++nf) {
        const int d = nf * 16 + lo;
        const int sw = ((d & 7) ^ (d >> 3)) << 3;
        const half8 vf = *reinterpret_cast<const half8*>(
            &VTs[d * RS_ + ((s * 32 + hi * 8) ^ sw)]);
        oacc[nf] = __builtin_amdgcn_mfma_f32_16x16x32_f16(pf, vf, oacc[nf], 0, 0, 0);
      }
    }
  }

  // normalize (per output row q2 = hi*4+r) and store
  float invl[4];
#pragma unroll
  for (int r = 0; r < 4; ++r) invl[r] = 1.f / __shfl(lrun, hi * 4 + r, 64);
#pragma unroll
  for (int nf = 0; nf < 4; ++nf)
#pragma unroll
    for (int r = 0; r < 4; ++r) {
      const int q = qt * 64 + wave * 16 + hi * 4 + r;
      O[((size_t)b * T_ + q) * D_ + h * 64 + nf * 16 + lo] = oacc[nf][r] * invl[r];
    }
}

// ---------------------------------------------------------------------------
// Cross-attention with band mask |t-j|<=4. Q: [B*T,256], KV: [B*S,512] (k|v).
// One thread per (b,t,h); at most 9 keys, softmax fully in registers.
// ---------------------------------------------------------------------------
__global__ __launch_bounds__(256) void cross_attn(
    const float* __restrict__ Q, const float* __restrict__ KV,
    float* __restrict__ O) {
  const int gid = blockIdx.x * 256 + threadIdx.x;  // 0 .. B*T*H-1
  const int h = gid & 3;
  const int bt = gid >> 2;
  const int t = bt & (T_ - 1);
  const int b = bt >> 10;

  float q[64];
  const float* qp = Q + (size_t)bt * D_ + h * 64;
#pragma unroll
  for (int d0 = 0; d0 < 64; d0 += 4) {
    const float4 v = *reinterpret_cast<const float4*>(qp + d0);
    q[d0] = v.x; q[d0 + 1] = v.y; q[d0 + 2] = v.z; q[d0 + 3] = v.w;
  }

  const int j0 = (t - WIN_ > 0) ? t - WIN_ : 0;
  const int j1 = (t + WIN_ < S_ - 1) ? t + WIN_ : S_ - 1;
  const int nj = j1 - j0 + 1;

  float sc[9];
  float mx = -1e30f;
#pragma unroll
  for (int jj = 0; jj < 9; ++jj) {
    if (jj < nj) {
      const float* kp = KV + ((size_t)b * S_ + j0 + jj) * 512 + h * 64;
      float s = 0.f;
#pragma unroll
      for (int d0 = 0; d0 < 64; d0 += 4) {
        const float4 kv = *reinterpret_cast<const float4*>(kp + d0);
        s += q[d0] * kv.x + q[d0 + 1] * kv.y + q[d0 + 2] * kv.z + q[d0 + 3] * kv.w;
      }
      sc[jj] = s * 0.125f;
      mx = fmaxf(mx, sc[jj]);
    } else {
      sc[jj] = -1e30f;
    }
  }
  float l = 0.f;
  float p[9];
#pragma unroll
  for (int jj = 0; jj < 9; ++jj) { p[jj] = __expf(sc[jj] - mx); l += p[jj]; }
  const float inv = 1.f / l;

  float o[64];
#pragma unroll
  for (int d = 0; d < 64; ++d) o[d] = 0.f;
#pragma unroll
  for (int jj = 0; jj < 9; ++jj) {
    if (jj < nj) {
      const float pj = p[jj] * inv;
      const float* vp = KV + ((size_t)b * S_ + j0 + jj) * 512 + 256 + h * 64;
#pragma unroll
      for (int d0 = 0; d0 < 64; d0 += 4) {
        const float4 vv = *reinterpret_cast<const float4*>(vp + d0);
        o[d0] += pj * vv.x; o[d0 + 1] += pj * vv.y;
        o[d0 + 2] += pj * vv.z; o[d0 + 3] += pj * vv.w;
      }
    }
  }
  float* op = O + (size_t)bt * D_ + h * 64;
#pragma unroll
  for (int d = 0; d < 64; ++d) op[d] = o[d];
}

// ---------------------------------------------------------------------------
// Out = LayerNorm(X + R) * g + b.   One wave per 256-wide row. Out may == X.
// ---------------------------------------------------------------------------
__global__ __launch_bounds__(256) void ln_res(
    const float* X, const float* __restrict__ R,
    const float* __restrict__ g, const float* __restrict__ bta, float* Out) {
  const int wid = threadIdx.x >> 6, lane = threadIdx.x & 63;
  const size_t row = (size_t)blockIdx.x * 4 + wid;
  const float* xp = X + row * D_;
  const float* rp = R + row * D_;
  float v[4];
  float s = 0.f;
#pragma unroll
  for (int k = 0; k < 4; ++k) {
    const int d = lane + k * 64;
    v[k] = xp[d] + rp[d];
    s += v[k];
  }
#pragma unroll
  for (int off = 32; off; off >>= 1) s += __shfl_xor(s, off, 64);
  const float mu = s * (1.f / 256.f);
  float var = 0.f;
#pragma unroll
  for (int k = 0; k < 4; ++k) { const float d = v[k] - mu; var += d * d; }
#pragma unroll
  for (int off = 32; off; off >>= 1) var += __shfl_xor(var, off, 64);
  const float rs = rsqrtf(var * (1.f / 256.f) + 1e-5f);
#pragma unroll
  for (int k = 0; k < 4; ++k) {
    const int d = lane + k * 64;
    Out[row * D_ + d] = (v[k] - mu) * rs * g[d] + bta[d];
  }
}

// ---------------------------------------------------------------------------
// out = clip(x @ W_vr.T + b_vr, 0, 1).  One thread per (row, j<33).
// ---------------------------------------------------------------------------
__global__ __launch_bounds__(256) void head_clip(
    const float* __restrict__ X, const float* __restrict__ Wv,
    const float* __restrict__ bv, float* __restrict__ Out) {
  const int gid = blockIdx.x * 256 + threadIdx.x;
  if (gid >= M_ * MOTION_) return;
  const int j = gid % MOTION_;
  const int row = gid / MOTION_;
  const float4* xr = reinterpret_cast<const float4*>(X + (size_t)row * D_);
  const float4* wr = reinterpret_cast<const float4*>(Wv + (size_t)j * D_);
  float acc = bv[j];
#pragma unroll
  for (int i = 0; i < 64; ++i) {
    const float4 a = xr[i], w = wr[i];
    acc += a.x * w.x + a.y * w.y + a.z * w.z + a.w * w.w;
  }
  Out[gid] = fminf(fmaxf(acc, 0.f), 1.f);
}

// ---------------------------------------------------------------------------
extern "C" void kernel_launch(void* const* d_in, const int* in_sizes, int n_in,
                              void* d_out, int out_size, void* d_ws, size_t ws_size,
                              hipStream_t stream) {
  (void)in_sizes; (void)n_in; (void)out_size; (void)ws_size;
  const float* hidden = (const float*)d_in[0];
  const float* tmot   = (const float*)d_in[1];
  const float* W_af   = (const float*)d_in[2];
  const float* b_af   = (const float*)d_in[3];
  const float* c1w    = (const float*)d_in[4];
  const float* c1b    = (const float*)d_in[5];
  const float* c2w    = (const float*)d_in[6];
  const float* c2b    = (const float*)d_in[7];
  const float* Wvm    = (const float*)d_in[8];
  const float* bvm    = (const float*)d_in[9];
  const float* sa_in_w  = (const float*)d_in[10];
  const float* sa_in_b  = (const float*)d_in[11];
  const float* sa_out_w = (const float*)d_in[12];
  const float* sa_out_b = (const float*)d_in[13];
  const float* ca_in_w  = (const float*)d_in[14];
  const float* ca_in_b  = (const float*)d_in[15];
  const float* ca_out_w = (const float*)d_in[16];
  const float* ca_out_b = (const float*)d_in[17];
  const float* ln1g = (const float*)d_in[18];
  const float* ln1b = (const float*)d_in[19];
  const float* ln2g = (const float*)d_in[20];
  const float* ln2b = (const float*)d_in[21];
  const float* ln3g = (const float*)d_in[22];
  const float* ln3b = (const float*)d_in[23];
  const float* ff1w = (const float*)d_in[24];
  const float* ff1b = (const float*)d_in[25];
  const float* ff2w = (const float*)d_in[26];
  const float* ff2b = (const float*)d_in[27];
  const float* Wvr  = (const float*)d_in[28];
  const float* bvr  = (const float*)d_in[29];
  float* out = (float*)d_out;

  float* ws = (float*)d_ws;
  const size_t BSD = (size_t)B_ * T_ * D_;  // 2,097,152 floats
  float* audio = ws;            // [B*S, 256]
  float* x     = ws + BSD;      // [B*T, 256]
  float* att   = ws + 2 * BSD;  // [B*T, 256]
  float* t1    = ws + 3 * BSD;  // [B*T, 256] scratch (conv1 output)
  float* qkv   = ws + 4 * BSD;  // [B*T, 768] / reused for q, kv, ffn hidden

  const dim3 blk(256);

  // audio front-end
  gemm_mfma<<<dim3(M_ / 64, D_ / 64), blk, 0, stream>>>(hidden, W_af, b_af, audio, M_, D_, AUDIO_, 0);
  conv_mfma<<<dim3(M_ / 64, D_ / 64), blk, 0, stream>>>(audio, c1w, c1b, t1, 0);
  conv_mfma<<<dim3(M_ / 64, D_ / 64), blk, 0, stream>>>(t1, c2w, c2b, audio, 1);

  // motion embedding + PE
  motion_pe<<<dim3(M_), blk, 0, stream>>>(tmot, Wvm, bvm, x);

  for (int l = 0; l < 2; ++l) {
    // self-attention
    gemm_mfma<<<dim3(M_ / 64, 768 / 64), blk, 0, stream>>>(
        x, sa_in_w + (size_t)l * 768 * 256, sa_in_b + l * 768, qkv, M_, 768, 256, 0);
    self_attn<<<dim3(T_ / 64, H_, B_), blk, 0, stream>>>(qkv, att);
    gemm_mfma<<<dim3(M_ / 64, 256 / 64), blk, 0, stream>>>(
        att, sa_out_w + (size_t)l * 256 * 256, sa_out_b + l * 256, t1, M_, 256, 256, 0);
    ln_res<<<dim3(M_ / 4), blk, 0, stream>>>(x, t1, ln1g + l * 256, ln1b + l * 256, x);

    // cross-attention (banded)
    gemm_mfma<<<dim3(M_ / 64, 256 / 64), blk, 0, stream>>>(
        x, ca_in_w + (size_t)l * 768 * 256, ca_in_b + l * 768, qkv, M_, 256, 256, 0);
    gemm_mfma<<<dim3(M_ / 64, 512 / 64), blk, 0, stream>>>(
        audio, ca_in_w + (size_t)l * 768 * 256 + 256 * 256, ca_in_b + l * 768 + 256,
        qkv + BSD, M_, 512, 256, 0);
    cross_attn<<<dim3(M_ * H_ / 256), blk, 0, stream>>>(qkv, qkv + BSD, att);
    gemm_mfma<<<dim3(M_ / 64, 256 / 64), blk, 0, stream>>>(
        att, ca_out_w + (size_t)l * 256 * 256, ca_out_b + l * 256, t1, M_, 256, 256, 0);
    ln_res<<<dim3(M_ / 4), blk, 0, stream>>>(x, t1, ln2g + l * 256, ln2b + l * 256, x);

    // FFN
    gemm_mfma<<<dim3(M_ / 64, 512 / 64), blk, 0, stream>>>(
        x, ff1w + (size_t)l * 512 * 256, ff1b + l * 512, qkv, M_, 512, 256, 1);
    gemm_mfma<<<dim3(M_ / 64, 256 / 64), blk, 0, stream>>>(
        qkv, ff2w + (size_t)l * 256 * 512, ff2b + l * 256, t1, M_, 256, 512, 0);
    ln_res<<<dim3(M_ / 4), blk, 0, stream>>>(x, t1, ln3g + l * 256, ln3b + l * 256, x);
  }

  head_clip<<<dim3((M_ * MOTION_ + 255) / 256), blk, 0, stream>>>(x, Wvr, bvr, out);
}